// Round 11
// baseline (1679.616 us; speedup 1.0000x reference)
//
#include <hip/hip_runtime.h>
#include <cstdint>

#define HIDDEN  128
#define NLAYERS 6
#define NNODES  50000
#define NEDGES  640000

typedef short short8 __attribute__((ext_vector_type(8)));
typedef float f32x4  __attribute__((ext_vector_type(4)));

// ---- bf16 <-> f32 helpers (RNE) -------------------------------------------
__device__ __forceinline__ float bf2f(unsigned short u) {
    return __uint_as_float(((unsigned int)u) << 16);
}
__device__ __forceinline__ unsigned short f2bf(float f) {
    unsigned int u = __float_as_uint(f);
    unsigned int r = u + 0x7FFFu + ((u >> 16) & 1u);
    return (unsigned short)(r >> 16);
}
__device__ __forceinline__ unsigned int pack2(float a, float b) {
    return (unsigned int)f2bf(a) | ((unsigned int)f2bf(b) << 16);
}
__device__ __forceinline__ void unpack8(uint4 v, float* f) {
    f[0] = bf2f((unsigned short)(v.x & 0xffff)); f[1] = bf2f((unsigned short)(v.x >> 16));
    f[2] = bf2f((unsigned short)(v.y & 0xffff)); f[3] = bf2f((unsigned short)(v.y >> 16));
    f[4] = bf2f((unsigned short)(v.z & 0xffff)); f[5] = bf2f((unsigned short)(v.z >> 16));
    f[6] = bf2f((unsigned short)(v.w & 0xffff)); f[7] = bf2f((unsigned short)(v.w >> 16));
}

// ---------------------------------------------------------------------------
// Index dtype detection + canonicalization
// ---------------------------------------------------------------------------
__global__ void detect_kernel(const int* __restrict__ ei, int* __restrict__ flag)
{
    int lane = threadIdx.x;
    int v = ei[2 * lane + 1];
    unsigned long long b = __ballot(v != 0);
    if (lane == 0) *flag = (b != 0ULL) ? 1 : 0;
}

__global__ void normidx_kernel(const int* __restrict__ ei, const int* __restrict__ flag,
                               int* __restrict__ s32, int* __restrict__ d32)
{
    int e = blockIdx.x * blockDim.x + threadIdx.x;
    if (e >= NEDGES) return;
    int s, d;
    if (*flag) { s = ei[e]; d = ei[NEDGES + e]; }
    else       { s = ei[2 * e]; d = ei[2 * (NEDGES + e)]; }
    s32[e] = min(max(s, 0), NNODES - 1);
    d32[e] = min(max(d, 0), NNODES - 1);
}

__global__ void degree_kernel(const int* __restrict__ dst, int* __restrict__ deg)
{
    int e = blockIdx.x * blockDim.x + threadIdx.x;
    if (e < NEDGES) atomicAdd(&deg[dst[e]], 1);
}

// ---------------------------------------------------------------------------
// Exclusive scan over deg[0..NNODES) -> off, cursor. One 1024-thread block.
// ---------------------------------------------------------------------------
#define SCAN_T 1024
__global__ void scan_kernel(const int* __restrict__ deg, int* __restrict__ off,
                            int* __restrict__ cursor)
{
    __shared__ int part[SCAN_T];
    const int t = threadIdx.x;
    const int CH = (NNODES + SCAN_T - 1) / SCAN_T;
    const int base = t * CH;
    int s = 0;
    for (int i = 0; i < CH; ++i) {
        int idx = base + i;
        if (idx < NNODES) s += deg[idx];
    }
    part[t] = s;
    __syncthreads();
    for (int d = 1; d < SCAN_T; d <<= 1) {
        int v = (t >= d) ? part[t - d] : 0;
        __syncthreads();
        part[t] += v;
        __syncthreads();
    }
    int run = (t == 0) ? 0 : part[t - 1];
    for (int i = 0; i < CH; ++i) {
        int idx = base + i;
        if (idx < NNODES) {
            off[idx] = run;
            cursor[idx] = run;
            run += deg[idx];
        }
    }
    if (t == SCAN_T - 1) off[NNODES] = run;
}

__global__ void scatter_kernel(const int* __restrict__ s32, const int* __restrict__ d32,
                               int* __restrict__ cursor,
                               int* __restrict__ sp, int* __restrict__ dp, int* __restrict__ ep)
{
    int e = blockIdx.x * blockDim.x + threadIdx.x;
    if (e >= NEDGES) return;
    int d = d32[e];
    int p = atomicAdd(&cursor[d], 1);
    sp[p] = s32[e];
    dp[p] = d;
    ep[p] = e;
}

// ---------------------------------------------------------------------------
// Weight transpose+convert: W [L][K][N] fp32 -> WT [L][N][K] bf16 (edge path)
// ---------------------------------------------------------------------------
__global__ void transpose_kernel(const float* __restrict__ W, unsigned short* __restrict__ WT,
                                 int K, int N, int L)
{
    long idx = (long)blockIdx.x * 256 + threadIdx.x;
    long tot = (long)L * K * N;
    if (idx >= tot) return;
    int kn = (int)(idx % ((long)K * N));
    int l  = (int)(idx / ((long)K * N));
    int k = kn / N;
    int n = kn % N;
    WT[(long)l * K * N + (long)n * K + k] = f2bf(W[idx]);
}

// ---------------------------------------------------------------------------
// Weight swizzle (node path): W [L][Ktot][128] fp32 -> fragment-ordered bf16.
// out[l][(c*8+nt)*512 + lane*8 + j] = W[l][k0+c*32+(lane>>4)*8+j][nt*16+(lane&15)]
// One wave B-fragment load = one coalesced 1024B read. (validated r9)
// ---------------------------------------------------------------------------
__global__ void swizzle_kernel(const float* __restrict__ W, unsigned short* __restrict__ out,
                               int k0, int Ktot, int Ksw, int L)
{
    long per = (long)Ksw * 128;
    long idx = (long)blockIdx.x * 256 + threadIdx.x;
    if (idx >= (long)L * per) return;
    int l = (int)(idx / per);
    int o = (int)(idx % per);
    int j    = o & 7;
    int lane = (o >> 3) & 63;
    int frag = o >> 9;                 // c*8 + nt
    int c = frag >> 3, nt = frag & 7;
    int k = k0 + c * 32 + (lane >> 4) * 8 + j;
    int n = nt * 16 + (lane & 15);
    out[idx] = f2bf(W[(long)l * Ktot * 128 + (long)k * 128 + n]);
}

// ---------------------------------------------------------------------------
// Encoder into permuted layout: ef[p] = enc(ea[ep[p]])
// ---------------------------------------------------------------------------
__global__ void encode_kernel(const float* __restrict__ ea,
                              const float* __restrict__ w,
                              const float* __restrict__ b,
                              const int* __restrict__ ep,
                              unsigned short* __restrict__ ef)
{
    int idx = blockIdx.x * blockDim.x + threadIdx.x;
    int p = idx >> 5;
    if (p >= NEDGES) return;
    int e = ep[p];
    int j = (idx & 31) << 2;
    float a0 = ea[e * 3 + 0], a1 = ea[e * 3 + 1], a2 = ea[e * 3 + 2];
    float4 w0 = *(const float4*)(w + 0 * HIDDEN + j);
    float4 w1 = *(const float4*)(w + 1 * HIDDEN + j);
    float4 w2 = *(const float4*)(w + 2 * HIDDEN + j);
    float4 bb = *(const float4*)(b + j);
    ushort4 o;
    o.x = f2bf(fmaf(a0, w0.x, fmaf(a1, w1.x, fmaf(a2, w2.x, bb.x))));
    o.y = f2bf(fmaf(a0, w0.y, fmaf(a1, w1.y, fmaf(a2, w2.y, bb.y))));
    o.z = f2bf(fmaf(a0, w0.z, fmaf(a1, w1.z, fmaf(a2, w2.z, bb.z))));
    o.w = f2bf(fmaf(a0, w0.w, fmaf(a1, w1.w, fmaf(a2, w2.w, bb.w))));
    *(ushort4*)(ef + (long)p * HIDDEN + j) = o;
}

// ---------------------------------------------------------------------------
// MFMA edge layer — UNCHANGED from round 10 (best variant).
// ---------------------------------------------------------------------------
__global__ __launch_bounds__(256, 3)
void edge_layer_mfma(const unsigned short* __restrict__ Xa,   // [N][128] bf16
                     const unsigned short* __restrict__ Xb,   // [N][128] bf16
                     unsigned short* __restrict__ ef,
                     float* __restrict__ sums,
                     const int* __restrict__ sp,
                     const int* __restrict__ dp,
                     const unsigned short* __restrict__ W1T,  // [128][384] bf16; W1c at k+256
                     const float* __restrict__ b1,
                     const unsigned short* __restrict__ W2T,  // [128][128] bf16
                     const float* __restrict__ b2)
{
    __shared__ __align__(16) unsigned char buf[45056];
    unsigned short* As = (unsigned short*)buf;
    unsigned short* Hs = (unsigned short*)buf;
    unsigned short* Bs = (unsigned short*)(buf + 34816);
    __shared__ int dv[128];
    __shared__ int sv[128];

    const int tid = threadIdx.x;
    const long eb = (long)blockIdx.x * 128;
    if (tid < 128) dv[tid]       = dp[eb + tid];
    else           sv[tid - 128] = sp[eb + tid - 128];

    const int lane = tid & 63;
    const int wv   = tid >> 6;
    const int mn   = lane & 15;
    const int q    = lane >> 4;
    const int rr   = tid >> 1;
    const int o    = (tid & 1) << 4;
    const int bn   = tid >> 1;
    const int bk   = (tid & 1) << 4;

    f32x4 acc[2][8];
#pragma unroll
    for (int h = 0; h < 2; ++h)
#pragma unroll
        for (int t = 0; t < 8; ++t) acc[h][t] = (f32x4)0.0f;

    short8 efold0[4], efold1[4];

    uint4 pa0, pa1, pw0, pw1;
    {
        const unsigned short* epp = ef + (eb + rr) * HIDDEN + o;
        pa0 = *(const uint4*)epp;
        pa1 = *(const uint4*)(epp + 8);
        const unsigned short* wp = W1T + (long)bn * 384 + 256 + bk;
        pw0 = *(const uint4*)wp;
        pw1 = *(const uint4*)(wp + 8);
    }

    for (int c = 0; c < 4; ++c) {
        *(uint4*)&As[rr * 40 + o]      = pa0;
        *(uint4*)&As[rr * 40 + o + 8]  = pa1;
        *(uint4*)&Bs[bn * 40 + bk]     = pw0;
        *(uint4*)&Bs[bn * 40 + bk + 8] = pw1;
        __syncthreads();

        if (c + 1 < 4) {
            const int cn = c + 1;
            const unsigned short* epp = ef + (eb + rr) * HIDDEN + (cn << 5) + o;
            pa0 = *(const uint4*)epp;
            pa1 = *(const uint4*)(epp + 8);
            const unsigned short* wp = W1T + (long)bn * 384 + 256 + (cn << 5) + bk;
            pw0 = *(const uint4*)wp;
            pw1 = *(const uint4*)(wp + 8);
        }

        short8 af0 = *(short8*)&As[(wv * 32 + mn) * 40 + (q << 3)];
        short8 af1 = *(short8*)&As[(wv * 32 + 16 + mn) * 40 + (q << 3)];
        efold0[c] = af0;
        efold1[c] = af1;
#pragma unroll
        for (int nt = 0; nt < 8; ++nt) {
            short8 bf = *(short8*)&Bs[(nt * 16 + mn) * 40 + (q << 3)];
            acc[0][nt] = __builtin_amdgcn_mfma_f32_16x16x32_bf16(af0, bf, acc[0][nt], 0, 0, 0);
            acc[1][nt] = __builtin_amdgcn_mfma_f32_16x16x32_bf16(af1, bf, acc[1][nt], 0, 0, 0);
        }
        __syncthreads();
    }

#pragma unroll
    for (int h = 0; h < 2; ++h)
#pragma unroll
        for (int nt = 0; nt < 8; ++nt)
#pragma unroll
            for (int r = 0; r < 4; ++r)
                Hs[(wv * 32 + h * 16 + q * 4 + r) * 136 + nt * 16 + mn] = f2bf(acc[h][nt][r]);

    {
        const int row  = wv * 32 + (lane >> 1);
        const int ch   = (lane & 1) << 6;
        const unsigned short* xap = Xa + (long)dv[row] * HIDDEN + ch;
        const unsigned short* xbp = Xb + (long)sv[row] * HIDDEN + ch;
        unsigned short* hp = &Hs[row * 136 + ch];
#pragma unroll
        for (int i = 0; i < 8; ++i) {
            uint4 va = *(const uint4*)(xap + (i << 3));
            uint4 vb = *(const uint4*)(xbp + (i << 3));
            uint4 vp = *(uint4*)(hp + (i << 3));
            float fa[8], fb[8], fp[8];
            unpack8(va, fa); unpack8(vb, fb); unpack8(vp, fp);
            const float* bp = b1 + ch + (i << 3);
            uint4 nw;
            float h0 = fmaxf(fp[0] + fa[0] + fb[0] + bp[0], 0.0f);
            float h1 = fmaxf(fp[1] + fa[1] + fb[1] + bp[1], 0.0f);
            float h2 = fmaxf(fp[2] + fa[2] + fb[2] + bp[2], 0.0f);
            float h3 = fmaxf(fp[3] + fa[3] + fb[3] + bp[3], 0.0f);
            float h4 = fmaxf(fp[4] + fa[4] + fb[4] + bp[4], 0.0f);
            float h5 = fmaxf(fp[5] + fa[5] + fb[5] + bp[5], 0.0f);
            float h6 = fmaxf(fp[6] + fa[6] + fb[6] + bp[6], 0.0f);
            float h7 = fmaxf(fp[7] + fa[7] + fb[7] + bp[7], 0.0f);
            nw.x = pack2(h0, h1); nw.y = pack2(h2, h3);
            nw.z = pack2(h4, h5); nw.w = pack2(h6, h7);
            *(uint4*)(hp + (i << 3)) = nw;
        }
    }

    f32x4 acc2[2][8];
#pragma unroll
    for (int h = 0; h < 2; ++h)
#pragma unroll
        for (int t = 0; t < 8; ++t) acc2[h][t] = (f32x4)0.0f;
    {
        const unsigned short* wp = W2T + (long)bn * 128 + bk;
        pw0 = *(const uint4*)wp;
        pw1 = *(const uint4*)(wp + 8);
    }
    for (int c = 0; c < 4; ++c) {
        *(uint4*)&Bs[bn * 40 + bk]     = pw0;
        *(uint4*)&Bs[bn * 40 + bk + 8] = pw1;
        __syncthreads();
        if (c + 1 < 4) {
            const unsigned short* wp = W2T + (long)bn * 128 + ((c + 1) << 5) + bk;
            pw0 = *(const uint4*)wp;
            pw1 = *(const uint4*)(wp + 8);
        }
        short8 af0 = *(short8*)&Hs[(wv * 32 + mn) * 136 + (c << 5) + (q << 3)];
        short8 af1 = *(short8*)&Hs[(wv * 32 + 16 + mn) * 136 + (c << 5) + (q << 3)];
#pragma unroll
        for (int nt = 0; nt < 8; ++nt) {
            short8 bf = *(short8*)&Bs[(nt * 16 + mn) * 40 + (q << 3)];
            acc2[0][nt] = __builtin_amdgcn_mfma_f32_16x16x32_bf16(af0, bf, acc2[0][nt], 0, 0, 0);
            acc2[1][nt] = __builtin_amdgcn_mfma_f32_16x16x32_bf16(af1, bf, acc2[1][nt], 0, 0, 0);
        }
        __syncthreads();
    }

#pragma unroll
    for (int h = 0; h < 2; ++h)
#pragma unroll
        for (int nt = 0; nt < 8; ++nt) {
            float b2v = b2[nt * 16 + mn];
#pragma unroll
            for (int r = 0; r < 4; ++r)
                Hs[(wv * 32 + h * 16 + q * 4 + r) * 136 + nt * 16 + mn] = f2bf(acc2[h][nt][r] + b2v);
        }

#pragma unroll
    for (int h = 0; h < 2; ++h) {
        const int row = wv * 32 + h * 16 + mn;
        unsigned short* ep_ = ef + (eb + row) * HIDDEN + (q << 3);
#pragma unroll
        for (int c = 0; c < 4; ++c) {
            uint4 mh = *(uint4*)&Hs[row * 136 + (c << 5) + (q << 3)];
            float m[8], e[8];
            unpack8(mh, m);
            short8 eo = h ? efold1[c] : efold0[c];
            uint4 eu = *(uint4*)&eo;
            unpack8(eu, e);
            uint4 nw;
            nw.x = pack2(e[0] + m[0], e[1] + m[1]);
            nw.y = pack2(e[2] + m[2], e[3] + m[3]);
            nw.z = pack2(e[4] + m[4], e[5] + m[5]);
            nw.w = pack2(e[6] + m[6], e[7] + m[7]);
            *(uint4*)(ep_ + (c << 5)) = nw;
        }
    }

    {
        const int cp = (tid & 63) << 1;
        const int qr = tid >> 6;
        float s0 = 0.0f, s1 = 0.0f;
        int cur = dv[qr * 32];
        for (int r = 0; r < 32; ++r) {
            const int row = qr * 32 + r;
            const int d = dv[row];
            if (d != cur) {
                atomicAdd(&sums[(long)cur * HIDDEN + cp], s0);
                atomicAdd(&sums[(long)cur * HIDDEN + cp + 1], s1);
                s0 = 0.0f; s1 = 0.0f;
                cur = d;
            }
            unsigned int u = *(unsigned int*)&Hs[row * 136 + cp];
            s0 += bf2f((unsigned short)(u & 0xffff));
            s1 += bf2f((unsigned short)(u >> 16));
        }
        atomicAdd(&sums[(long)cur * HIDDEN + cp], s0);
        atomicAdd(&sums[(long)cur * HIDDEN + cp + 1], s1);
    }
}

// ---------------------------------------------------------------------------
// Node layer, BARRIER-FREE: 32 nodes/block, 128 threads (2 waves), every LDS
// band wave-private (stage rows tid>>2 land in owning wave's band; DS ops are
// wave-ordered). B operands direct from swizzled global (coalesced 1024B/wave).
//   GEMM1: A=[x|sums*cInv] staged bf16 (As), B=N1S
//   GEMM2: A=Hs(H), B=N2S ; xnew=x+acc2+b2 fp32 ; Hs<-xnew
//   Xa/Xb: A=Hs(xnew), B=W1An/W1Bn ; sums rows zeroed after staging.
// ---------------------------------------------------------------------------
__global__ __launch_bounds__(128, 4)
void node_layer_mfma(float* __restrict__ x,
                     float* __restrict__ sums,
                     const int* __restrict__ deg,
                     const unsigned short* __restrict__ N1S,  // swizzled [8][8][512]
                     const float* __restrict__ b1,
                     const unsigned short* __restrict__ N2S,  // swizzled [4][8][512]
                     const float* __restrict__ b2,
                     const unsigned short* __restrict__ W1An, // swizzled (or null)
                     const unsigned short* __restrict__ W1Bn,
                     unsigned short* __restrict__ Xa,
                     unsigned short* __restrict__ Xb)
{
    __shared__ __align__(16) unsigned short As[32 * 264];    // 16896 B
    __shared__ __align__(16) unsigned short Hs[32 * 136];    //  8704 B

    const int tid  = threadIdx.x;
    const long n0  = (long)blockIdx.x * 32;
    const int lane = tid & 63;
    const int wv   = tid >> 6;       // 0 or 1
    const int mn   = lane & 15;
    const int q    = lane >> 4;

    // ---- stage A (rows tid>>2: wave0 -> 0..15, wave1 -> 16..31: own band) ----
    {
        const int row = tid >> 2;
        const int qt  = (tid & 3) << 5;
        long nr = n0 + row; if (nr >= NNODES) nr = NNODES - 1;
        const float ci = 1.0f / fmaxf((float)deg[nr], 1.0f);
        const float* xr = x + nr * HIDDEN + qt;
        const float* sr = sums + nr * HIDDEN + qt;
#pragma unroll
        for (int i = 0; i < 4; ++i) {
            float4 v0 = *(const float4*)(xr + i * 8);
            float4 v1 = *(const float4*)(xr + i * 8 + 4);
            uint4 u;
            u.x = pack2(v0.x, v0.y); u.y = pack2(v0.z, v0.w);
            u.z = pack2(v1.x, v1.y); u.w = pack2(v1.z, v1.w);
            *(uint4*)&As[row * 264 + qt + i * 8] = u;
            float4 w0 = *(const float4*)(sr + i * 8);
            float4 w1 = *(const float4*)(sr + i * 8 + 4);
            u.x = pack2(w0.x * ci, w0.y * ci); u.y = pack2(w0.z * ci, w0.w * ci);
            u.z = pack2(w1.x * ci, w1.y * ci); u.w = pack2(w1.z * ci, w1.w * ci);
            *(uint4*)&As[row * 264 + 128 + qt + i * 8] = u;
        }
        // zero own sums quarter for next layer (row is block-private)
        if (n0 + row < NNODES) {
            float4 z = make_float4(0.f, 0.f, 0.f, 0.f);
            float* p = sums + nr * HIDDEN + qt;
#pragma unroll
            for (int i = 0; i < 8; ++i) ((float4*)p)[i] = z;
        }
    }
    // no barrier: GEMM1 A-reads are own-band, DS wave-ordered

    // ---- GEMM1: K=256, A from As, B direct swizzled ----
    f32x4 acc[8];
#pragma unroll
    for (int t = 0; t < 8; ++t) acc[t] = (f32x4)0.0f;
#pragma unroll
    for (int c = 0; c < 8; ++c) {
        short8 af = *(short8*)&As[(wv * 16 + mn) * 264 + (c << 5) + (q << 3)];
#pragma unroll
        for (int nt = 0; nt < 8; ++nt) {
            short8 bf = *(const short8*)(N1S + (c * 8 + nt) * 512 + lane * 8);
            acc[nt] = __builtin_amdgcn_mfma_f32_16x16x32_bf16(af, bf, acc[nt], 0, 0, 0);
        }
    }

    // ---- H = relu(acc + b1) -> Hs (own band) ----
#pragma unroll
    for (int nt = 0; nt < 8; ++nt) {
        float b1v = b1[nt * 16 + mn];
#pragma unroll
        for (int r = 0; r < 4; ++r) {
            float hv = fmaxf(acc[nt][r] + b1v, 0.0f);
            Hs[(wv * 16 + q * 4 + r) * 136 + nt * 16 + mn] = f2bf(hv);
        }
    }

    // ---- GEMM2: A from Hs (own band), B direct ----
    f32x4 acc2[8];
#pragma unroll
    for (int t = 0; t < 8; ++t) acc2[t] = (f32x4)0.0f;
#pragma unroll
    for (int c = 0; c < 4; ++c) {
        short8 af = *(short8*)&Hs[(wv * 16 + mn) * 136 + (c << 5) + (q << 3)];
#pragma unroll
        for (int nt = 0; nt < 8; ++nt) {
            short8 bf = *(const short8*)(N2S + (c * 8 + nt) * 512 + lane * 8);
            acc2[nt] = __builtin_amdgcn_mfma_f32_16x16x32_bf16(af, bf, acc2[nt], 0, 0, 0);
        }
    }

    // ---- xnew = x + acc2 + b2 (fp32); Hs <- xnew bf16 (own band, after reads) ----
#pragma unroll
    for (int nt = 0; nt < 8; ++nt) {
        float b2v = b2[nt * 16 + mn];
#pragma unroll
        for (int r = 0; r < 4; ++r) {
            long row = n0 + wv * 16 + q * 4 + r;
            float xn = 0.0f;
            if (row < NNODES) {
                float* p = x + row * HIDDEN + nt * 16 + mn;
                xn = *p + acc2[nt][r] + b2v;
                *p = xn;
            }
            Hs[(wv * 16 + q * 4 + r) * 136 + nt * 16 + mn] = f2bf(xn);
        }
    }

    // ---- Xa/Xb for next layer: xnew @ W1a / W1b (A own band, B direct) ----
    if (W1An) {
#pragma unroll
        for (int half = 0; half < 2; ++half) {
            const unsigned short* Bsw = half ? W1Bn : W1An;
            f32x4 accN[8];
#pragma unroll
            for (int t = 0; t < 8; ++t) accN[t] = (f32x4)0.0f;
#pragma unroll
            for (int c = 0; c < 4; ++c) {
                short8 af = *(short8*)&Hs[(wv * 16 + mn) * 136 + (c << 5) + (q << 3)];
#pragma unroll
                for (int nt = 0; nt < 8; ++nt) {
                    short8 bf = *(const short8*)(Bsw + (c * 8 + nt) * 512 + lane * 8);
                    accN[nt] = __builtin_amdgcn_mfma_f32_16x16x32_bf16(af, bf, accN[nt], 0, 0, 0);
                }
            }
            unsigned short* Xout = half ? Xb : Xa;
#pragma unroll
            for (int nt = 0; nt < 8; ++nt) {
#pragma unroll
                for (int r = 0; r < 4; ++r) {
                    long row = n0 + wv * 16 + q * 4 + r;
                    if (row < NNODES) {
                        Xout[row * HIDDEN + nt * 16 + mn] = f2bf(accN[nt][r]);
                    }
                }
            }
        }
    }
}

// ---------------------------------------------------------------------------
// Decoder + row L2-normalize (one wave per node)
// ---------------------------------------------------------------------------
__global__ void decode_kernel(const float* __restrict__ x,
                              const float* __restrict__ w,
                              const float* __restrict__ b,
                              float* __restrict__ out)
{
    int gid = blockIdx.x * blockDim.x + threadIdx.x;
    int node = gid >> 6;
    int lane = threadIdx.x & 63;
    if (node >= NNODES) return;
    float a0 = 0.f, a1 = 0.f, a2 = 0.f;
#pragma unroll
    for (int k = lane; k < HIDDEN; k += 64) {
        float xv = x[(long)node * HIDDEN + k];
        a0 = fmaf(xv, w[k * 3 + 0], a0);
        a1 = fmaf(xv, w[k * 3 + 1], a1);
        a2 = fmaf(xv, w[k * 3 + 2], a2);
    }
#pragma unroll
    for (int off = 32; off > 0; off >>= 1) {
        a0 += __shfl_down(a0, off);
        a1 += __shfl_down(a1, off);
        a2 += __shfl_down(a2, off);
    }
    if (lane == 0) {
        a0 += b[0]; a1 += b[1]; a2 += b[2];
        float nrm = sqrtf(a0 * a0 + a1 * a1 + a2 * a2);
        float inv = 1.0f / fmaxf(nrm, 1e-12f);
        out[(long)node * 3 + 0] = a0 * inv;
        out[(long)node * 3 + 1] = a1 * inv;
        out[(long)node * 3 + 2] = a2 * inv;
    }
}

// ---------------------------------------------------------------------------
extern "C" void kernel_launch(void* const* d_in, const int* in_sizes, int n_in,
                              void* d_out, int out_size, void* d_ws, size_t ws_size,
                              hipStream_t stream)
{
    const float* edge_attr = (const float*)d_in[1];
    const int*   ei        = (const int*)d_in[2];
    const float* enc_w     = (const float*)d_in[3];
    const float* enc_b     = (const float*)d_in[4];
    const float* dec_w     = (const float*)d_in[5];
    const float* dec_b     = (const float*)d_in[6];
    const float* edge_w1   = (const float*)d_in[7];
    const float* edge_b1   = (const float*)d_in[8];
    const float* edge_w2   = (const float*)d_in[9];
    const float* edge_b2   = (const float*)d_in[10];
    const float* node_w1   = (const float*)d_in[11];
    const float* node_b1   = (const float*)d_in[12];
    const float* node_w2   = (const float*)d_in[13];
    const float* node_b2   = (const float*)d_in[14];

    // workspace layout (bytes), 16B-aligned, total ~255.8 MB
    char* ws = (char*)d_ws;
    unsigned short* ef  = (unsigned short*)(ws);                  // 163,840,000
    float* x      = (float*)(ws + 163840000L);                    //  25,600,000
    float* sums   = (float*)(ws + 189440000L);                    //  25,600,000
    int*   src32  = (int*)  (ws + 215040000L);                    //   2,560,000
    int*   dst32  = (int*)  (ws + 217600000L);                    //   2,560,000
    int*   sp     = (int*)  (ws + 220160000L);                    //   2,560,000
    int*   dp     = (int*)  (ws + 222720000L);                    //   2,560,000
    int*   eperm  = (int*)  (ws + 225280000L);                    //   2,560,000
    int*   deg    = (int*)  (ws + 227840000L);                    //     200,704
    int*   off    = (int*)  (ws + 228040704L);                    //     200,704
    int*   cursor = (int*)  (ws + 228241408L);                    //     200,704
    int*   flag   = (int*)  (ws + 228442112L);                    //          64
    unsigned short* W1T = (unsigned short*)(ws + 228442176L);     //     589,824 (edge)
    unsigned short* W2T = (unsigned short*)(ws + 229032000L);     //     196,608 (edge)
    unsigned short* N1S = (unsigned short*)(ws + 229228608L);     //     393,216 (node, swizzled)
    unsigned short* N2S = (unsigned short*)(ws + 229621824L);     //     196,608
    unsigned short* W1A = (unsigned short*)(ws + 229818432L);     //     196,608
    unsigned short* W1B = (unsigned short*)(ws + 230015040L);     //     196,608
    unsigned short* Xa  = (unsigned short*)(ws + 230211648L);     //  12,800,000
    unsigned short* Xb  = (unsigned short*)(ws + 243011648L);     //  12,800,000
    // end: 255,811,648

    float* out = (float*)d_out;

    hipMemsetAsync(x, 0, (size_t)NNODES * HIDDEN * sizeof(float), stream);
    hipMemsetAsync(sums, 0, (size_t)NNODES * HIDDEN * sizeof(float), stream);
    hipMemsetAsync(deg, 0, 200704, stream);
    hipMemsetAsync(Xa, 0, 25600000, stream);   // Xa + Xb (contiguous)

    detect_kernel<<<1, 64, 0, stream>>>(ei, flag);
    normidx_kernel<<<(NEDGES + 255) / 256, 256, 0, stream>>>(ei, flag, src32, dst32);
    degree_kernel<<<(NEDGES + 255) / 256, 256, 0, stream>>>(dst32, deg);
    scan_kernel<<<1, SCAN_T, 0, stream>>>(deg, off, cursor);
    scatter_kernel<<<(NEDGES + 255) / 256, 256, 0, stream>>>(src32, dst32, cursor, sp, dp, eperm);
    encode_kernel<<<(NEDGES * 32 + 255) / 256, 256, 0, stream>>>(edge_attr, enc_w, enc_b, eperm, ef);

    transpose_kernel<<<(6 * 384 * 128 + 255) / 256, 256, 0, stream>>>(edge_w1, W1T, 384, 128, 6);
    transpose_kernel<<<(6 * 128 * 128 + 255) / 256, 256, 0, stream>>>(edge_w2, W2T, 128, 128, 6);
    swizzle_kernel<<<(6 * 256 * 128 + 255) / 256, 256, 0, stream>>>(node_w1, N1S, 0,   256, 256, 6);
    swizzle_kernel<<<(6 * 128 * 128 + 255) / 256, 256, 0, stream>>>(node_w2, N2S, 0,   128, 128, 6);
    swizzle_kernel<<<(6 * 128 * 128 + 255) / 256, 256, 0, stream>>>(edge_w1, W1A, 0,   384, 128, 6);
    swizzle_kernel<<<(6 * 128 * 128 + 255) / 256, 256, 0, stream>>>(edge_w1, W1B, 128, 384, 128, 6);

    for (int l = 0; l < NLAYERS; ++l) {
        edge_layer_mfma<<<NEDGES / 128, 256, 0, stream>>>(
            Xa, Xb, ef, sums, sp, dp,
            W1T + (long)l * 384 * 128, edge_b1 + (long)l * HIDDEN,
            W2T + (long)l * 128 * 128, edge_b2 + (long)l * HIDDEN);
        const unsigned short* w1an = (l + 1 < NLAYERS) ? (W1A + (long)(l + 1) * 16384) : nullptr;
        const unsigned short* w1bn = (l + 1 < NLAYERS) ? (W1B + (long)(l + 1) * 16384) : nullptr;
        node_layer_mfma<<<(NNODES + 31) / 32, 128, 0, stream>>>(
            x, sums, deg,
            N1S + (long)l * 32768, node_b1 + (long)l * HIDDEN,
            N2S + (long)l * 16384, node_b2 + (long)l * HIDDEN,
            w1an, w1bn, Xa, Xb);
    }

    decode_kernel<<<(NNODES * 64 + 255) / 256, 256, 0, stream>>>(x, dec_w, dec_b, out);
}

// Round 12
// 1592.209 us; speedup vs baseline: 1.0549x; 1.0549x over previous
//
#include <hip/hip_runtime.h>
#include <cstdint>

#define HIDDEN  128
#define NLAYERS 6
#define NNODES  50000
#define NEDGES  640000

typedef short short8 __attribute__((ext_vector_type(8)));
typedef float f32x4  __attribute__((ext_vector_type(4)));

// ---- bf16 <-> f32 helpers (RNE) -------------------------------------------
__device__ __forceinline__ float bf2f(unsigned short u) {
    return __uint_as_float(((unsigned int)u) << 16);
}
__device__ __forceinline__ unsigned short f2bf(float f) {
    unsigned int u = __float_as_uint(f);
    unsigned int r = u + 0x7FFFu + ((u >> 16) & 1u);
    return (unsigned short)(r >> 16);
}
__device__ __forceinline__ unsigned int pack2(float a, float b) {
    return (unsigned int)f2bf(a) | ((unsigned int)f2bf(b) << 16);
}
__device__ __forceinline__ void unpack8(uint4 v, float* f) {
    f[0] = bf2f((unsigned short)(v.x & 0xffff)); f[1] = bf2f((unsigned short)(v.x >> 16));
    f[2] = bf2f((unsigned short)(v.y & 0xffff)); f[3] = bf2f((unsigned short)(v.y >> 16));
    f[4] = bf2f((unsigned short)(v.z & 0xffff)); f[5] = bf2f((unsigned short)(v.z >> 16));
    f[6] = bf2f((unsigned short)(v.w & 0xffff)); f[7] = bf2f((unsigned short)(v.w >> 16));
}

// ---------------------------------------------------------------------------
// Index dtype detection + canonicalization
// ---------------------------------------------------------------------------
__global__ void detect_kernel(const int* __restrict__ ei, int* __restrict__ flag)
{
    int lane = threadIdx.x;
    int v = ei[2 * lane + 1];
    unsigned long long b = __ballot(v != 0);
    if (lane == 0) *flag = (b != 0ULL) ? 1 : 0;
}

__global__ void normidx_kernel(const int* __restrict__ ei, const int* __restrict__ flag,
                               int* __restrict__ s32, int* __restrict__ d32)
{
    int e = blockIdx.x * blockDim.x + threadIdx.x;
    if (e >= NEDGES) return;
    int s, d;
    if (*flag) { s = ei[e]; d = ei[NEDGES + e]; }
    else       { s = ei[2 * e]; d = ei[2 * (NEDGES + e)]; }
    s32[e] = min(max(s, 0), NNODES - 1);
    d32[e] = min(max(d, 0), NNODES - 1);
}

__global__ void degree_kernel(const int* __restrict__ dst, int* __restrict__ deg)
{
    int e = blockIdx.x * blockDim.x + threadIdx.x;
    if (e < NEDGES) atomicAdd(&deg[dst[e]], 1);
}

// ---------------------------------------------------------------------------
// Exclusive scan over deg[0..NNODES) -> off, cursor. One 1024-thread block.
// ---------------------------------------------------------------------------
#define SCAN_T 1024
__global__ void scan_kernel(const int* __restrict__ deg, int* __restrict__ off,
                            int* __restrict__ cursor)
{
    __shared__ int part[SCAN_T];
    const int t = threadIdx.x;
    const int CH = (NNODES + SCAN_T - 1) / SCAN_T;
    const int base = t * CH;
    int s = 0;
    for (int i = 0; i < CH; ++i) {
        int idx = base + i;
        if (idx < NNODES) s += deg[idx];
    }
    part[t] = s;
    __syncthreads();
    for (int d = 1; d < SCAN_T; d <<= 1) {
        int v = (t >= d) ? part[t - d] : 0;
        __syncthreads();
        part[t] += v;
        __syncthreads();
    }
    int run = (t == 0) ? 0 : part[t - 1];
    for (int i = 0; i < CH; ++i) {
        int idx = base + i;
        if (idx < NNODES) {
            off[idx] = run;
            cursor[idx] = run;
            run += deg[idx];
        }
    }
    if (t == SCAN_T - 1) off[NNODES] = run;
}

__global__ void scatter_kernel(const int* __restrict__ s32, const int* __restrict__ d32,
                               int* __restrict__ cursor,
                               int* __restrict__ sp, int* __restrict__ dp, int* __restrict__ ep)
{
    int e = blockIdx.x * blockDim.x + threadIdx.x;
    if (e >= NEDGES) return;
    int d = d32[e];
    int p = atomicAdd(&cursor[d], 1);
    sp[p] = s32[e];
    dp[p] = d;
    ep[p] = e;
}

// ---------------------------------------------------------------------------
// Weight transpose+convert: W [L][K][N] fp32 -> WT [L][N][K] bf16
// ---------------------------------------------------------------------------
__global__ void transpose_kernel(const float* __restrict__ W, unsigned short* __restrict__ WT,
                                 int K, int N, int L)
{
    long idx = (long)blockIdx.x * 256 + threadIdx.x;
    long tot = (long)L * K * N;
    if (idx >= tot) return;
    int kn = (int)(idx % ((long)K * N));
    int l  = (int)(idx / ((long)K * N));
    int k = kn / N;
    int n = kn % N;
    WT[(long)l * K * N + (long)n * K + k] = f2bf(W[idx]);
}

// ---------------------------------------------------------------------------
// Encoder into permuted layout: ef[p] = enc(ea[ep[p]])
// ---------------------------------------------------------------------------
__global__ void encode_kernel(const float* __restrict__ ea,
                              const float* __restrict__ w,
                              const float* __restrict__ b,
                              const int* __restrict__ ep,
                              unsigned short* __restrict__ ef)
{
    int idx = blockIdx.x * blockDim.x + threadIdx.x;
    int p = idx >> 5;
    if (p >= NEDGES) return;
    int e = ep[p];
    int j = (idx & 31) << 2;
    float a0 = ea[e * 3 + 0], a1 = ea[e * 3 + 1], a2 = ea[e * 3 + 2];
    float4 w0 = *(const float4*)(w + 0 * HIDDEN + j);
    float4 w1 = *(const float4*)(w + 1 * HIDDEN + j);
    float4 w2 = *(const float4*)(w + 2 * HIDDEN + j);
    float4 bb = *(const float4*)(b + j);
    ushort4 o;
    o.x = f2bf(fmaf(a0, w0.x, fmaf(a1, w1.x, fmaf(a2, w2.x, bb.x))));
    o.y = f2bf(fmaf(a0, w0.y, fmaf(a1, w1.y, fmaf(a2, w2.y, bb.y))));
    o.z = f2bf(fmaf(a0, w0.z, fmaf(a1, w1.z, fmaf(a2, w2.z, bb.z))));
    o.w = f2bf(fmaf(a0, w0.w, fmaf(a1, w1.w, fmaf(a2, w2.w, bb.w))));
    *(ushort4*)(ef + (long)p * HIDDEN + j) = o;
}

// ---------------------------------------------------------------------------
// MFMA edge layer — UNCHANGED from round 10 (best variant).
// ---------------------------------------------------------------------------
__global__ __launch_bounds__(256, 3)
void edge_layer_mfma(const unsigned short* __restrict__ Xa,   // [N][128] bf16
                     const unsigned short* __restrict__ Xb,   // [N][128] bf16
                     unsigned short* __restrict__ ef,
                     float* __restrict__ sums,
                     const int* __restrict__ sp,
                     const int* __restrict__ dp,
                     const unsigned short* __restrict__ W1T,  // [128][384] bf16; W1c at k+256
                     const float* __restrict__ b1,
                     const unsigned short* __restrict__ W2T,  // [128][128] bf16
                     const float* __restrict__ b2)
{
    __shared__ __align__(16) unsigned char buf[45056];
    unsigned short* As = (unsigned short*)buf;
    unsigned short* Hs = (unsigned short*)buf;
    unsigned short* Bs = (unsigned short*)(buf + 34816);
    __shared__ int dv[128];
    __shared__ int sv[128];

    const int tid = threadIdx.x;
    const long eb = (long)blockIdx.x * 128;
    if (tid < 128) dv[tid]       = dp[eb + tid];
    else           sv[tid - 128] = sp[eb + tid - 128];

    const int lane = tid & 63;
    const int wv   = tid >> 6;
    const int mn   = lane & 15;
    const int q    = lane >> 4;
    const int rr   = tid >> 1;
    const int o    = (tid & 1) << 4;
    const int bn   = tid >> 1;
    const int bk   = (tid & 1) << 4;

    f32x4 acc[2][8];
#pragma unroll
    for (int h = 0; h < 2; ++h)
#pragma unroll
        for (int t = 0; t < 8; ++t) acc[h][t] = (f32x4)0.0f;

    short8 efold0[4], efold1[4];

    uint4 pa0, pa1, pw0, pw1;
    {
        const unsigned short* epp = ef + (eb + rr) * HIDDEN + o;
        pa0 = *(const uint4*)epp;
        pa1 = *(const uint4*)(epp + 8);
        const unsigned short* wp = W1T + (long)bn * 384 + 256 + bk;
        pw0 = *(const uint4*)wp;
        pw1 = *(const uint4*)(wp + 8);
    }

    for (int c = 0; c < 4; ++c) {
        *(uint4*)&As[rr * 40 + o]      = pa0;
        *(uint4*)&As[rr * 40 + o + 8]  = pa1;
        *(uint4*)&Bs[bn * 40 + bk]     = pw0;
        *(uint4*)&Bs[bn * 40 + bk + 8] = pw1;
        __syncthreads();

        if (c + 1 < 4) {
            const int cn = c + 1;
            const unsigned short* epp = ef + (eb + rr) * HIDDEN + (cn << 5) + o;
            pa0 = *(const uint4*)epp;
            pa1 = *(const uint4*)(epp + 8);
            const unsigned short* wp = W1T + (long)bn * 384 + 256 + (cn << 5) + bk;
            pw0 = *(const uint4*)wp;
            pw1 = *(const uint4*)(wp + 8);
        }

        short8 af0 = *(short8*)&As[(wv * 32 + mn) * 40 + (q << 3)];
        short8 af1 = *(short8*)&As[(wv * 32 + 16 + mn) * 40 + (q << 3)];
        efold0[c] = af0;
        efold1[c] = af1;
#pragma unroll
        for (int nt = 0; nt < 8; ++nt) {
            short8 bf = *(short8*)&Bs[(nt * 16 + mn) * 40 + (q << 3)];
            acc[0][nt] = __builtin_amdgcn_mfma_f32_16x16x32_bf16(af0, bf, acc[0][nt], 0, 0, 0);
            acc[1][nt] = __builtin_amdgcn_mfma_f32_16x16x32_bf16(af1, bf, acc[1][nt], 0, 0, 0);
        }
        __syncthreads();
    }

#pragma unroll
    for (int h = 0; h < 2; ++h)
#pragma unroll
        for (int nt = 0; nt < 8; ++nt)
#pragma unroll
            for (int r = 0; r < 4; ++r)
                Hs[(wv * 32 + h * 16 + q * 4 + r) * 136 + nt * 16 + mn] = f2bf(acc[h][nt][r]);

    {
        const int row  = wv * 32 + (lane >> 1);
        const int ch   = (lane & 1) << 6;
        const unsigned short* xap = Xa + (long)dv[row] * HIDDEN + ch;
        const unsigned short* xbp = Xb + (long)sv[row] * HIDDEN + ch;
        unsigned short* hp = &Hs[row * 136 + ch];
#pragma unroll
        for (int i = 0; i < 8; ++i) {
            uint4 va = *(const uint4*)(xap + (i << 3));
            uint4 vb = *(const uint4*)(xbp + (i << 3));
            uint4 vp = *(uint4*)(hp + (i << 3));
            float fa[8], fb[8], fp[8];
            unpack8(va, fa); unpack8(vb, fb); unpack8(vp, fp);
            const float* bp = b1 + ch + (i << 3);
            uint4 nw;
            float h0 = fmaxf(fp[0] + fa[0] + fb[0] + bp[0], 0.0f);
            float h1 = fmaxf(fp[1] + fa[1] + fb[1] + bp[1], 0.0f);
            float h2 = fmaxf(fp[2] + fa[2] + fb[2] + bp[2], 0.0f);
            float h3 = fmaxf(fp[3] + fa[3] + fb[3] + bp[3], 0.0f);
            float h4 = fmaxf(fp[4] + fa[4] + fb[4] + bp[4], 0.0f);
            float h5 = fmaxf(fp[5] + fa[5] + fb[5] + bp[5], 0.0f);
            float h6 = fmaxf(fp[6] + fa[6] + fb[6] + bp[6], 0.0f);
            float h7 = fmaxf(fp[7] + fa[7] + fb[7] + bp[7], 0.0f);
            nw.x = pack2(h0, h1); nw.y = pack2(h2, h3);
            nw.z = pack2(h4, h5); nw.w = pack2(h6, h7);
            *(uint4*)(hp + (i << 3)) = nw;
        }
    }

    f32x4 acc2[2][8];
#pragma unroll
    for (int h = 0; h < 2; ++h)
#pragma unroll
        for (int t = 0; t < 8; ++t) acc2[h][t] = (f32x4)0.0f;
    {
        const unsigned short* wp = W2T + (long)bn * 128 + bk;
        pw0 = *(const uint4*)wp;
        pw1 = *(const uint4*)(wp + 8);
    }
    for (int c = 0; c < 4; ++c) {
        *(uint4*)&Bs[bn * 40 + bk]     = pw0;
        *(uint4*)&Bs[bn * 40 + bk + 8] = pw1;
        __syncthreads();
        if (c + 1 < 4) {
            const unsigned short* wp = W2T + (long)bn * 128 + ((c + 1) << 5) + bk;
            pw0 = *(const uint4*)wp;
            pw1 = *(const uint4*)(wp + 8);
        }
        short8 af0 = *(short8*)&Hs[(wv * 32 + mn) * 136 + (c << 5) + (q << 3)];
        short8 af1 = *(short8*)&Hs[(wv * 32 + 16 + mn) * 136 + (c << 5) + (q << 3)];
#pragma unroll
        for (int nt = 0; nt < 8; ++nt) {
            short8 bf = *(short8*)&Bs[(nt * 16 + mn) * 40 + (q << 3)];
            acc2[0][nt] = __builtin_amdgcn_mfma_f32_16x16x32_bf16(af0, bf, acc2[0][nt], 0, 0, 0);
            acc2[1][nt] = __builtin_amdgcn_mfma_f32_16x16x32_bf16(af1, bf, acc2[1][nt], 0, 0, 0);
        }
        __syncthreads();
    }

#pragma unroll
    for (int h = 0; h < 2; ++h)
#pragma unroll
        for (int nt = 0; nt < 8; ++nt) {
            float b2v = b2[nt * 16 + mn];
#pragma unroll
            for (int r = 0; r < 4; ++r)
                Hs[(wv * 32 + h * 16 + q * 4 + r) * 136 + nt * 16 + mn] = f2bf(acc2[h][nt][r] + b2v);
        }

#pragma unroll
    for (int h = 0; h < 2; ++h) {
        const int row = wv * 32 + h * 16 + mn;
        unsigned short* ep_ = ef + (eb + row) * HIDDEN + (q << 3);
#pragma unroll
        for (int c = 0; c < 4; ++c) {
            uint4 mh = *(uint4*)&Hs[row * 136 + (c << 5) + (q << 3)];
            float m[8], e[8];
            unpack8(mh, m);
            short8 eo = h ? efold1[c] : efold0[c];
            uint4 eu = *(uint4*)&eo;
            unpack8(eu, e);
            uint4 nw;
            nw.x = pack2(e[0] + m[0], e[1] + m[1]);
            nw.y = pack2(e[2] + m[2], e[3] + m[3]);
            nw.z = pack2(e[4] + m[4], e[5] + m[5]);
            nw.w = pack2(e[6] + m[6], e[7] + m[7]);
            *(uint4*)(ep_ + (c << 5)) = nw;
        }
    }

    {
        const int cp = (tid & 63) << 1;
        const int qr = tid >> 6;
        float s0 = 0.0f, s1 = 0.0f;
        int cur = dv[qr * 32];
        for (int r = 0; r < 32; ++r) {
            const int row = qr * 32 + r;
            const int d = dv[row];
            if (d != cur) {
                atomicAdd(&sums[(long)cur * HIDDEN + cp], s0);
                atomicAdd(&sums[(long)cur * HIDDEN + cp + 1], s1);
                s0 = 0.0f; s1 = 0.0f;
                cur = d;
            }
            unsigned int u = *(unsigned int*)&Hs[row * 136 + cp];
            s0 += bf2f((unsigned short)(u & 0xffff));
            s1 += bf2f((unsigned short)(u >> 16));
        }
        atomicAdd(&sums[(long)cur * HIDDEN + cp], s0);
        atomicAdd(&sums[(long)cur * HIDDEN + cp + 1], s1);
    }
}

// ---------------------------------------------------------------------------
// MFMA node layer: r10 staged structure + DOUBLE-WIDE B staging (64 K/stage):
// barriers 40 -> 20. A-staging is wave-private (rows tid>>2 in own band).
// Stage sources: s<2 -> x, s>=2 -> sums*cInv (per-thread cInv from deg[]).
// ---------------------------------------------------------------------------
__global__ __launch_bounds__(256, 4)
void node_layer_mfma(float* __restrict__ x,
                     float* __restrict__ sums,
                     const int* __restrict__ deg,
                     const unsigned short* __restrict__ N1T,  // [128][256] bf16
                     const float* __restrict__ b1,
                     const unsigned short* __restrict__ N2T,  // [128][128] bf16
                     const float* __restrict__ b2,
                     const unsigned short* __restrict__ W1Tn, // [128][384] next layer (or null)
                     unsigned short* __restrict__ Xa,
                     unsigned short* __restrict__ Xb)
{
    __shared__ __align__(16) unsigned short As[64 * 72];     //  9216 B
    __shared__ __align__(16) unsigned short Bs[128 * 72];    // 18432 B
    __shared__ __align__(16) unsigned short Hs[64 * 136];    // 17408 B

    const int tid  = threadIdx.x;
    const long n0  = (long)blockIdx.x * 64;
    const int lane = tid & 63;
    const int wv   = tid >> 6;
    const int mn   = lane & 15;
    const int q    = lane >> 4;
    const int srow = tid >> 2;          // 0..63 (wave-private band)
    const int sseg = tid & 3;           // 16-elem segment of 64
    const int bn   = tid >> 1;          // 0..127
    const int bk   = (tid & 1) << 4;    // 0 or 16

    long nr = n0 + srow;
    if (nr >= NNODES) nr = NNODES - 1;
    const float ci = 1.0f / fmaxf((float)deg[nr], 1.0f);

    f32x4 acc[8];
#pragma unroll
    for (int t = 0; t < 8; ++t) acc[t] = (f32x4)0.0f;

    float4 qa0, qa1, qa2, qa3;
    uint4 pb0, pb1, pb2, pb3;
    {   // stage 0 loads (A: x k[0,64); B: N1T k[0,64))
        const float* ap = x + nr * HIDDEN + sseg * 16;
        qa0 = *(const float4*)ap;       qa1 = *(const float4*)(ap + 4);
        qa2 = *(const float4*)(ap + 8); qa3 = *(const float4*)(ap + 12);
        const unsigned short* wp = N1T + (long)bn * 256 + bk;
        pb0 = *(const uint4*)wp;        pb1 = *(const uint4*)(wp + 8);
        pb2 = *(const uint4*)(wp + 32); pb3 = *(const uint4*)(wp + 40);
    }
    float scCur = 1.0f;
    // ---- GEMM1: K=256 in 4 stages of 64 ----
    for (int s = 0; s < 4; ++s) {
        {
            uint4 u;
            u.x = pack2(qa0.x * scCur, qa0.y * scCur); u.y = pack2(qa0.z * scCur, qa0.w * scCur);
            u.z = pack2(qa1.x * scCur, qa1.y * scCur); u.w = pack2(qa1.z * scCur, qa1.w * scCur);
            *(uint4*)&As[srow * 72 + sseg * 16] = u;
            u.x = pack2(qa2.x * scCur, qa2.y * scCur); u.y = pack2(qa2.z * scCur, qa2.w * scCur);
            u.z = pack2(qa3.x * scCur, qa3.y * scCur); u.w = pack2(qa3.z * scCur, qa3.w * scCur);
            *(uint4*)&As[srow * 72 + sseg * 16 + 8] = u;
        }
        *(uint4*)&Bs[bn * 72 + bk]          = pb0;
        *(uint4*)&Bs[bn * 72 + bk + 8]      = pb1;
        *(uint4*)&Bs[bn * 72 + 32 + bk]     = pb2;
        *(uint4*)&Bs[bn * 72 + 32 + bk + 8] = pb3;
        __syncthreads();
        if (s + 1 < 4) {
            const int sn = s + 1;
            const float* base = (sn < 2) ? x : sums;
            scCur = (sn < 2) ? 1.0f : ci;
            const float* ap = base + nr * HIDDEN + ((sn & 1) << 6) + sseg * 16;
            qa0 = *(const float4*)ap;       qa1 = *(const float4*)(ap + 4);
            qa2 = *(const float4*)(ap + 8); qa3 = *(const float4*)(ap + 12);
            const unsigned short* wp = N1T + (long)bn * 256 + (sn << 6) + bk;
            pb0 = *(const uint4*)wp;        pb1 = *(const uint4*)(wp + 8);
            pb2 = *(const uint4*)(wp + 32); pb3 = *(const uint4*)(wp + 40);
        }
#pragma unroll
        for (int cc = 0; cc < 2; ++cc) {
            short8 af = *(short8*)&As[(wv * 16 + mn) * 72 + (cc << 5) + (q << 3)];
#pragma unroll
            for (int nt = 0; nt < 8; ++nt) {
                short8 bf = *(short8*)&Bs[(nt * 16 + mn) * 72 + (cc << 5) + (q << 3)];
                acc[nt] = __builtin_amdgcn_mfma_f32_16x16x32_bf16(af, bf, acc[nt], 0, 0, 0);
            }
        }
        __syncthreads();
    }

    // zero own sums rows for the next layer (all sums loads issued above)
    if (n0 + srow < NNODES) {
        float4 z = make_float4(0.f, 0.f, 0.f, 0.f);
        float* p = sums + nr * HIDDEN + (sseg << 5);
#pragma unroll
        for (int i = 0; i < 8; ++i) ((float4*)p)[i] = z;
    }

    // ---- H = relu(acc + b1) -> Hs (own wave band; no barrier needed) ----
#pragma unroll
    for (int nt = 0; nt < 8; ++nt) {
        float b1v = b1[nt * 16 + mn];
#pragma unroll
        for (int r = 0; r < 4; ++r) {
            float hv = fmaxf(acc[nt][r] + b1v, 0.0f);
            Hs[(wv * 16 + q * 4 + r) * 136 + nt * 16 + mn] = f2bf(hv);
        }
    }

    // ---- GEMM2: K=128 in 2 stages of 64 ----
    f32x4 acc2[8];
#pragma unroll
    for (int t = 0; t < 8; ++t) acc2[t] = (f32x4)0.0f;
    {
        const unsigned short* wp = N2T + (long)bn * 128 + bk;
        pb0 = *(const uint4*)wp;        pb1 = *(const uint4*)(wp + 8);
        pb2 = *(const uint4*)(wp + 32); pb3 = *(const uint4*)(wp + 40);
    }
    for (int s = 0; s < 2; ++s) {
        *(uint4*)&Bs[bn * 72 + bk]          = pb0;
        *(uint4*)&Bs[bn * 72 + bk + 8]      = pb1;
        *(uint4*)&Bs[bn * 72 + 32 + bk]     = pb2;
        *(uint4*)&Bs[bn * 72 + 32 + bk + 8] = pb3;
        __syncthreads();
        if (s + 1 < 2) {
            const unsigned short* wp = N2T + (long)bn * 128 + 64 + bk;
            pb0 = *(const uint4*)wp;        pb1 = *(const uint4*)(wp + 8);
            pb2 = *(const uint4*)(wp + 32); pb3 = *(const uint4*)(wp + 40);
        }
#pragma unroll
        for (int cc = 0; cc < 2; ++cc) {
            short8 af = *(short8*)&Hs[(wv * 16 + mn) * 136 + (s << 6) + (cc << 5) + (q << 3)];
#pragma unroll
            for (int nt = 0; nt < 8; ++nt) {
                short8 bf = *(short8*)&Bs[(nt * 16 + mn) * 72 + (cc << 5) + (q << 3)];
                acc2[nt] = __builtin_amdgcn_mfma_f32_16x16x32_bf16(af, bf, acc2[nt], 0, 0, 0);
            }
        }
        __syncthreads();
    }

    // ---- xnew = x + acc2 + b2 (exact fp32); Hs <- xnew bf16 (own band) ----
#pragma unroll
    for (int nt = 0; nt < 8; ++nt) {
        float b2v = b2[nt * 16 + mn];
#pragma unroll
        for (int r = 0; r < 4; ++r) {
            long row = n0 + wv * 16 + q * 4 + r;
            float xn = 0.0f;
            if (row < NNODES) {
                float* p = x + row * HIDDEN + nt * 16 + mn;
                xn = *p + acc2[nt][r] + b2v;
                *p = xn;
            }
            Hs[(wv * 16 + q * 4 + r) * 136 + nt * 16 + mn] = f2bf(xn);
        }
    }

    // ---- Xa/Xb for next layer: xnew @ W1a / W1b, 2 stages of 64 each ----
    if (W1Tn) {
#pragma unroll
        for (int half = 0; half < 2; ++half) {
            const int kbase = half << 7;
            f32x4 accN[8];
#pragma unroll
            for (int t = 0; t < 8; ++t) accN[t] = (f32x4)0.0f;
            {
                const unsigned short* wp = W1Tn + (long)bn * 384 + kbase + bk;
                pb0 = *(const uint4*)wp;        pb1 = *(const uint4*)(wp + 8);
                pb2 = *(const uint4*)(wp + 32); pb3 = *(const uint4*)(wp + 40);
            }
            for (int s = 0; s < 2; ++s) {
                *(uint4*)&Bs[bn * 72 + bk]          = pb0;
                *(uint4*)&Bs[bn * 72 + bk + 8]      = pb1;
                *(uint4*)&Bs[bn * 72 + 32 + bk]     = pb2;
                *(uint4*)&Bs[bn * 72 + 32 + bk + 8] = pb3;
                __syncthreads();
                if (s + 1 < 2) {
                    const unsigned short* wp = W1Tn + (long)bn * 384 + kbase + 64 + bk;
                    pb0 = *(const uint4*)wp;        pb1 = *(const uint4*)(wp + 8);
                    pb2 = *(const uint4*)(wp + 32); pb3 = *(const uint4*)(wp + 40);
                }
#pragma unroll
                for (int cc = 0; cc < 2; ++cc) {
                    short8 af = *(short8*)&Hs[(wv * 16 + mn) * 136 + (s << 6) + (cc << 5) + (q << 3)];
#pragma unroll
                    for (int nt = 0; nt < 8; ++nt) {
                        short8 bf = *(short8*)&Bs[(nt * 16 + mn) * 72 + (cc << 5) + (q << 3)];
                        accN[nt] = __builtin_amdgcn_mfma_f32_16x16x32_bf16(af, bf, accN[nt], 0, 0, 0);
                    }
                }
                __syncthreads();
            }
            unsigned short* Xout = half ? Xb : Xa;
#pragma unroll
            for (int nt = 0; nt < 8; ++nt) {
#pragma unroll
                for (int r = 0; r < 4; ++r) {
                    long row = n0 + wv * 16 + q * 4 + r;
                    if (row < NNODES) {
                        Xout[row * HIDDEN + nt * 16 + mn] = f2bf(accN[nt][r]);
                    }
                }
            }
        }
    }
}

// ---------------------------------------------------------------------------
// Decoder + row L2-normalize (one wave per node)
// ---------------------------------------------------------------------------
__global__ void decode_kernel(const float* __restrict__ x,
                              const float* __restrict__ w,
                              const float* __restrict__ b,
                              float* __restrict__ out)
{
    int gid = blockIdx.x * blockDim.x + threadIdx.x;
    int node = gid >> 6;
    int lane = threadIdx.x & 63;
    if (node >= NNODES) return;
    float a0 = 0.f, a1 = 0.f, a2 = 0.f;
#pragma unroll
    for (int k = lane; k < HIDDEN; k += 64) {
        float xv = x[(long)node * HIDDEN + k];
        a0 = fmaf(xv, w[k * 3 + 0], a0);
        a1 = fmaf(xv, w[k * 3 + 1], a1);
        a2 = fmaf(xv, w[k * 3 + 2], a2);
    }
#pragma unroll
    for (int off = 32; off > 0; off >>= 1) {
        a0 += __shfl_down(a0, off);
        a1 += __shfl_down(a1, off);
        a2 += __shfl_down(a2, off);
    }
    if (lane == 0) {
        a0 += b[0]; a1 += b[1]; a2 += b[2];
        float nrm = sqrtf(a0 * a0 + a1 * a1 + a2 * a2);
        float inv = 1.0f / fmaxf(nrm, 1e-12f);
        out[(long)node * 3 + 0] = a0 * inv;
        out[(long)node * 3 + 1] = a1 * inv;
        out[(long)node * 3 + 2] = a2 * inv;
    }
}

// ---------------------------------------------------------------------------
extern "C" void kernel_launch(void* const* d_in, const int* in_sizes, int n_in,
                              void* d_out, int out_size, void* d_ws, size_t ws_size,
                              hipStream_t stream)
{
    const float* edge_attr = (const float*)d_in[1];
    const int*   ei        = (const int*)d_in[2];
    const float* enc_w     = (const float*)d_in[3];
    const float* enc_b     = (const float*)d_in[4];
    const float* dec_w     = (const float*)d_in[5];
    const float* dec_b     = (const float*)d_in[6];
    const float* edge_w1   = (const float*)d_in[7];
    const float* edge_b1   = (const float*)d_in[8];
    const float* edge_w2   = (const float*)d_in[9];
    const float* edge_b2   = (const float*)d_in[10];
    const float* node_w1   = (const float*)d_in[11];
    const float* node_b1   = (const float*)d_in[12];
    const float* node_w2   = (const float*)d_in[13];
    const float* node_b2   = (const float*)d_in[14];

    // workspace layout (bytes), 16B-aligned, total ~255.4 MB
    char* ws = (char*)d_ws;
    unsigned short* ef  = (unsigned short*)(ws);                  // 163,840,000
    float* x      = (float*)(ws + 163840000L);                    //  25,600,000
    float* sums   = (float*)(ws + 189440000L);                    //  25,600,000
    int*   src32  = (int*)  (ws + 215040000L);                    //   2,560,000
    int*   dst32  = (int*)  (ws + 217600000L);                    //   2,560,000
    int*   sp     = (int*)  (ws + 220160000L);                    //   2,560,000
    int*   dp     = (int*)  (ws + 222720000L);                    //   2,560,000
    int*   eperm  = (int*)  (ws + 225280000L);                    //   2,560,000
    int*   deg    = (int*)  (ws + 227840000L);                    //     200,704
    int*   off    = (int*)  (ws + 228040704L);                    //     200,704
    int*   cursor = (int*)  (ws + 228241408L);                    //     200,704
    int*   flag   = (int*)  (ws + 228442112L);                    //          64
    unsigned short* W1T = (unsigned short*)(ws + 228442176L);     //     589,824
    unsigned short* W2T = (unsigned short*)(ws + 229032000L);     //     196,608
    unsigned short* N1T = (unsigned short*)(ws + 229228608L);     //     393,216
    unsigned short* N2T = (unsigned short*)(ws + 229621824L);     //     196,608
    unsigned short* Xa  = (unsigned short*)(ws + 229818432L);     //  12,800,000
    unsigned short* Xb  = (unsigned short*)(ws + 242618432L);     //  12,800,000
    // end: 255,418,432

    float* out = (float*)d_out;

    hipMemsetAsync(x, 0, (size_t)NNODES * HIDDEN * sizeof(float), stream);
    hipMemsetAsync(sums, 0, (size_t)NNODES * HIDDEN * sizeof(float), stream);
    hipMemsetAsync(deg, 0, 200704, stream);
    hipMemsetAsync(Xa, 0, 25600000, stream);   // Xa + Xb (contiguous)

    detect_kernel<<<1, 64, 0, stream>>>(ei, flag);
    normidx_kernel<<<(NEDGES + 255) / 256, 256, 0, stream>>>(ei, flag, src32, dst32);
    degree_kernel<<<(NEDGES + 255) / 256, 256, 0, stream>>>(dst32, deg);
    scan_kernel<<<1, SCAN_T, 0, stream>>>(deg, off, cursor);
    scatter_kernel<<<(NEDGES + 255) / 256, 256, 0, stream>>>(src32, dst32, cursor, sp, dp, eperm);
    encode_kernel<<<(NEDGES * 32 + 255) / 256, 256, 0, stream>>>(edge_attr, enc_w, enc_b, eperm, ef);

    transpose_kernel<<<(6 * 384 * 128 + 255) / 256, 256, 0, stream>>>(edge_w1, W1T, 384, 128, 6);
    transpose_kernel<<<(6 * 128 * 128 + 255) / 256, 256, 0, stream>>>(edge_w2, W2T, 128, 128, 6);
    transpose_kernel<<<(6 * 256 * 128 + 255) / 256, 256, 0, stream>>>(node_w1, N1T, 256, 128, 6);
    transpose_kernel<<<(6 * 128 * 128 + 255) / 256, 256, 0, stream>>>(node_w2, N2T, 128, 128, 6);

    for (int l = 0; l < NLAYERS; ++l) {
        edge_layer_mfma<<<NEDGES / 128, 256, 0, stream>>>(
            Xa, Xb, ef, sums, sp, dp,
            W1T + (long)l * 384 * 128, edge_b1 + (long)l * HIDDEN,
            W2T + (long)l * 128 * 128, edge_b2 + (long)l * HIDDEN);
        const unsigned short* w1next = (l + 1 < NLAYERS) ? (W1T + (long)(l + 1) * 384 * 128) : nullptr;
        node_layer_mfma<<<(NNODES + 63) / 64, 256, 0, stream>>>(
            x, sums, deg,
            N1T + (long)l * 256 * 128, node_b1 + (long)l * HIDDEN,
            N2T + (long)l * 128 * 128, node_b2 + (long)l * HIDDEN,
            w1next, Xa, Xb);
    }

    decode_kernel<<<(NNODES * 64 + 255) / 256, 256, 0, stream>>>(x, dec_w, dec_b, out);
}

// Round 13
// 1557.555 us; speedup vs baseline: 1.0784x; 1.0222x over previous
//
#include <hip/hip_runtime.h>
#include <cstdint>

#define HIDDEN  128
#define NLAYERS 6
#define NNODES  50000
#define NEDGES  640000

typedef short short8 __attribute__((ext_vector_type(8)));
typedef float f32x4  __attribute__((ext_vector_type(4)));

#if defined(__has_builtin)
#if __has_builtin(__builtin_amdgcn_cvt_pk_bf16_f32)
#define HAS_PK_BF16 1
#endif
#endif

// ---- bf16 <-> f32 helpers (RNE) -------------------------------------------
__device__ __forceinline__ float bf2f(unsigned short u) {
    return __uint_as_float(((unsigned int)u) << 16);
}
__device__ __forceinline__ unsigned short f2bf(float f) {
    unsigned int u = __float_as_uint(f);
    unsigned int r = u + 0x7FFFu + ((u >> 16) & 1u);
    return (unsigned short)(r >> 16);
}
__device__ __forceinline__ unsigned int pack2(float a, float b) {
#ifdef HAS_PK_BF16
    typedef __bf16 bf16x2 __attribute__((ext_vector_type(2)));
    bf16x2 v = __builtin_amdgcn_cvt_pk_bf16_f32(a, b);
    unsigned int u;
    __builtin_memcpy(&u, &v, 4);
    return u;
#else
    return (unsigned int)f2bf(a) | ((unsigned int)f2bf(b) << 16);
#endif
}
__device__ __forceinline__ void unpack8(uint4 v, float* f) {
    f[0] = bf2f((unsigned short)(v.x & 0xffff)); f[1] = bf2f((unsigned short)(v.x >> 16));
    f[2] = bf2f((unsigned short)(v.y & 0xffff)); f[3] = bf2f((unsigned short)(v.y >> 16));
    f[4] = bf2f((unsigned short)(v.z & 0xffff)); f[5] = bf2f((unsigned short)(v.z >> 16));
    f[6] = bf2f((unsigned short)(v.w & 0xffff)); f[7] = bf2f((unsigned short)(v.w >> 16));
}

// ---------------------------------------------------------------------------
// Index dtype detection + canonicalization
// ---------------------------------------------------------------------------
__global__ void detect_kernel(const int* __restrict__ ei, int* __restrict__ flag)
{
    int lane = threadIdx.x;
    int v = ei[2 * lane + 1];
    unsigned long long b = __ballot(v != 0);
    if (lane == 0) *flag = (b != 0ULL) ? 1 : 0;
}

__global__ void normidx_kernel(const int* __restrict__ ei, const int* __restrict__ flag,
                               int* __restrict__ s32, int* __restrict__ d32)
{
    int e = blockIdx.x * blockDim.x + threadIdx.x;
    if (e >= NEDGES) return;
    int s, d;
    if (*flag) { s = ei[e]; d = ei[NEDGES + e]; }
    else       { s = ei[2 * e]; d = ei[2 * (NEDGES + e)]; }
    s32[e] = min(max(s, 0), NNODES - 1);
    d32[e] = min(max(d, 0), NNODES - 1);
}

__global__ void degree_kernel(const int* __restrict__ dst, int* __restrict__ deg)
{
    int e = blockIdx.x * blockDim.x + threadIdx.x;
    if (e < NEDGES) atomicAdd(&deg[dst[e]], 1);
}

// ---------------------------------------------------------------------------
// Exclusive scan over deg[0..NNODES) -> off, cursor. One 1024-thread block.
// ---------------------------------------------------------------------------
#define SCAN_T 1024
__global__ void scan_kernel(const int* __restrict__ deg, int* __restrict__ off,
                            int* __restrict__ cursor)
{
    __shared__ int part[SCAN_T];
    const int t = threadIdx.x;
    const int CH = (NNODES + SCAN_T - 1) / SCAN_T;
    const int base = t * CH;
    int s = 0;
    for (int i = 0; i < CH; ++i) {
        int idx = base + i;
        if (idx < NNODES) s += deg[idx];
    }
    part[t] = s;
    __syncthreads();
    for (int d = 1; d < SCAN_T; d <<= 1) {
        int v = (t >= d) ? part[t - d] : 0;
        __syncthreads();
        part[t] += v;
        __syncthreads();
    }
    int run = (t == 0) ? 0 : part[t - 1];
    for (int i = 0; i < CH; ++i) {
        int idx = base + i;
        if (idx < NNODES) {
            off[idx] = run;
            cursor[idx] = run;
            run += deg[idx];
        }
    }
    if (t == SCAN_T - 1) off[NNODES] = run;
}

__global__ void scatter_kernel(const int* __restrict__ s32, const int* __restrict__ d32,
                               int* __restrict__ cursor,
                               int* __restrict__ sp, int* __restrict__ dp, int* __restrict__ ep)
{
    int e = blockIdx.x * blockDim.x + threadIdx.x;
    if (e >= NEDGES) return;
    int d = d32[e];
    int p = atomicAdd(&cursor[d], 1);
    sp[p] = s32[e];
    dp[p] = d;
    ep[p] = e;
}

// ---------------------------------------------------------------------------
// Weight transpose+convert: W [L][K][N] fp32 -> WT [L][N][K] bf16
// ---------------------------------------------------------------------------
__global__ void transpose_kernel(const float* __restrict__ W, unsigned short* __restrict__ WT,
                                 int K, int N, int L)
{
    long idx = (long)blockIdx.x * 256 + threadIdx.x;
    long tot = (long)L * K * N;
    if (idx >= tot) return;
    int kn = (int)(idx % ((long)K * N));
    int l  = (int)(idx / ((long)K * N));
    int k = kn / N;
    int n = kn % N;
    WT[(long)l * K * N + (long)n * K + k] = f2bf(W[idx]);
}

// ---------------------------------------------------------------------------
// Encoder into permuted layout: ef[p] = enc(ea[ep[p]])
// ---------------------------------------------------------------------------
__global__ void encode_kernel(const float* __restrict__ ea,
                              const float* __restrict__ w,
                              const float* __restrict__ b,
                              const int* __restrict__ ep,
                              unsigned short* __restrict__ ef)
{
    int idx = blockIdx.x * blockDim.x + threadIdx.x;
    int p = idx >> 5;
    if (p >= NEDGES) return;
    int e = ep[p];
    int j = (idx & 31) << 2;
    float a0 = ea[e * 3 + 0], a1 = ea[e * 3 + 1], a2 = ea[e * 3 + 2];
    float4 w0 = *(const float4*)(w + 0 * HIDDEN + j);
    float4 w1 = *(const float4*)(w + 1 * HIDDEN + j);
    float4 w2 = *(const float4*)(w + 2 * HIDDEN + j);
    float4 bb = *(const float4*)(b + j);
    ushort4 o;
    o.x = f2bf(fmaf(a0, w0.x, fmaf(a1, w1.x, fmaf(a2, w2.x, bb.x))));
    o.y = f2bf(fmaf(a0, w0.y, fmaf(a1, w1.y, fmaf(a2, w2.y, bb.y))));
    o.z = f2bf(fmaf(a0, w0.z, fmaf(a1, w1.z, fmaf(a2, w2.z, bb.z))));
    o.w = f2bf(fmaf(a0, w0.w, fmaf(a1, w1.w, fmaf(a2, w2.w, bb.w))));
    *(ushort4*)(ef + (long)p * HIDDEN + j) = o;
}

// ---------------------------------------------------------------------------
// MFMA edge layer — r10 structure; bf16 packing via HW cvt_pk where available.
// ---------------------------------------------------------------------------
__global__ __launch_bounds__(256, 3)
void edge_layer_mfma(const unsigned short* __restrict__ Xa,   // [N][128] bf16
                     const unsigned short* __restrict__ Xb,   // [N][128] bf16
                     unsigned short* __restrict__ ef,
                     float* __restrict__ sums,
                     const int* __restrict__ sp,
                     const int* __restrict__ dp,
                     const unsigned short* __restrict__ W1T,  // [128][384] bf16; W1c at k+256
                     const float* __restrict__ b1,
                     const unsigned short* __restrict__ W2T,  // [128][128] bf16
                     const float* __restrict__ b2)
{
    __shared__ __align__(16) unsigned char buf[45056];
    unsigned short* As = (unsigned short*)buf;
    unsigned short* Hs = (unsigned short*)buf;
    unsigned short* Bs = (unsigned short*)(buf + 34816);
    __shared__ int dv[128];
    __shared__ int sv[128];

    const int tid = threadIdx.x;
    const long eb = (long)blockIdx.x * 128;
    if (tid < 128) dv[tid]       = dp[eb + tid];
    else           sv[tid - 128] = sp[eb + tid - 128];

    const int lane = tid & 63;
    const int wv   = tid >> 6;
    const int mn   = lane & 15;
    const int q    = lane >> 4;
    const int rr   = tid >> 1;
    const int o    = (tid & 1) << 4;
    const int bn   = tid >> 1;
    const int bk   = (tid & 1) << 4;

    f32x4 acc[2][8];
#pragma unroll
    for (int h = 0; h < 2; ++h)
#pragma unroll
        for (int t = 0; t < 8; ++t) acc[h][t] = (f32x4)0.0f;

    short8 efold0[4], efold1[4];

    uint4 pa0, pa1, pw0, pw1;
    {
        const unsigned short* epp = ef + (eb + rr) * HIDDEN + o;
        pa0 = *(const uint4*)epp;
        pa1 = *(const uint4*)(epp + 8);
        const unsigned short* wp = W1T + (long)bn * 384 + 256 + bk;
        pw0 = *(const uint4*)wp;
        pw1 = *(const uint4*)(wp + 8);
    }

    for (int c = 0; c < 4; ++c) {
        *(uint4*)&As[rr * 40 + o]      = pa0;
        *(uint4*)&As[rr * 40 + o + 8]  = pa1;
        *(uint4*)&Bs[bn * 40 + bk]     = pw0;
        *(uint4*)&Bs[bn * 40 + bk + 8] = pw1;
        __syncthreads();

        if (c + 1 < 4) {
            const int cn = c + 1;
            const unsigned short* epp = ef + (eb + rr) * HIDDEN + (cn << 5) + o;
            pa0 = *(const uint4*)epp;
            pa1 = *(const uint4*)(epp + 8);
            const unsigned short* wp = W1T + (long)bn * 384 + 256 + (cn << 5) + bk;
            pw0 = *(const uint4*)wp;
            pw1 = *(const uint4*)(wp + 8);
        }

        short8 af0 = *(short8*)&As[(wv * 32 + mn) * 40 + (q << 3)];
        short8 af1 = *(short8*)&As[(wv * 32 + 16 + mn) * 40 + (q << 3)];
        efold0[c] = af0;
        efold1[c] = af1;
#pragma unroll
        for (int nt = 0; nt < 8; ++nt) {
            short8 bf = *(short8*)&Bs[(nt * 16 + mn) * 40 + (q << 3)];
            acc[0][nt] = __builtin_amdgcn_mfma_f32_16x16x32_bf16(af0, bf, acc[0][nt], 0, 0, 0);
            acc[1][nt] = __builtin_amdgcn_mfma_f32_16x16x32_bf16(af1, bf, acc[1][nt], 0, 0, 0);
        }
        __syncthreads();
    }

    // ---- pre -> Hs (C-layout, own wave band; packed converts) ----
#pragma unroll
    for (int h = 0; h < 2; ++h)
#pragma unroll
        for (int nt = 0; nt < 8; ++nt)
#pragma unroll
            for (int rp = 0; rp < 2; ++rp) {
                unsigned int u = pack2(acc[h][nt][2 * rp], acc[h][nt][2 * rp + 1]);
                const int row = wv * 32 + h * 16 + q * 4 + 2 * rp;
                Hs[row * 136 + nt * 16 + mn]       = (unsigned short)u;
                Hs[(row + 1) * 136 + nt * 16 + mn] = (unsigned short)(u >> 16);
            }

    // ---- H = relu(pre + Xa[dst] + Xb[src] + b1), row-major, vector gather ----
    {
        const int row  = wv * 32 + (lane >> 1);
        const int ch   = (lane & 1) << 6;
        const unsigned short* xap = Xa + (long)dv[row] * HIDDEN + ch;
        const unsigned short* xbp = Xb + (long)sv[row] * HIDDEN + ch;
        unsigned short* hp = &Hs[row * 136 + ch];
#pragma unroll
        for (int i = 0; i < 8; ++i) {
            uint4 va = *(const uint4*)(xap + (i << 3));
            uint4 vb = *(const uint4*)(xbp + (i << 3));
            uint4 vp = *(uint4*)(hp + (i << 3));
            float fa[8], fb[8], fp[8];
            unpack8(va, fa); unpack8(vb, fb); unpack8(vp, fp);
            const float* bp = b1 + ch + (i << 3);
            uint4 nw;
            float h0 = fmaxf(fp[0] + fa[0] + fb[0] + bp[0], 0.0f);
            float h1 = fmaxf(fp[1] + fa[1] + fb[1] + bp[1], 0.0f);
            float h2 = fmaxf(fp[2] + fa[2] + fb[2] + bp[2], 0.0f);
            float h3 = fmaxf(fp[3] + fa[3] + fb[3] + bp[3], 0.0f);
            float h4 = fmaxf(fp[4] + fa[4] + fb[4] + bp[4], 0.0f);
            float h5 = fmaxf(fp[5] + fa[5] + fb[5] + bp[5], 0.0f);
            float h6 = fmaxf(fp[6] + fa[6] + fb[6] + bp[6], 0.0f);
            float h7 = fmaxf(fp[7] + fa[7] + fb[7] + bp[7], 0.0f);
            nw.x = pack2(h0, h1); nw.y = pack2(h2, h3);
            nw.z = pack2(h4, h5); nw.w = pack2(h6, h7);
            *(uint4*)(hp + (i << 3)) = nw;
        }
    }
    // No barrier: GEMM2 A-frags read only this wave's band (DS wave-ordered).

    f32x4 acc2[2][8];
#pragma unroll
    for (int h = 0; h < 2; ++h)
#pragma unroll
        for (int t = 0; t < 8; ++t) acc2[h][t] = (f32x4)0.0f;
    {
        const unsigned short* wp = W2T + (long)bn * 128 + bk;
        pw0 = *(const uint4*)wp;
        pw1 = *(const uint4*)(wp + 8);
    }
    for (int c = 0; c < 4; ++c) {
        *(uint4*)&Bs[bn * 40 + bk]     = pw0;
        *(uint4*)&Bs[bn * 40 + bk + 8] = pw1;
        __syncthreads();
        if (c + 1 < 4) {
            const unsigned short* wp = W2T + (long)bn * 128 + ((c + 1) << 5) + bk;
            pw0 = *(const uint4*)wp;
            pw1 = *(const uint4*)(wp + 8);
        }
        short8 af0 = *(short8*)&Hs[(wv * 32 + mn) * 136 + (c << 5) + (q << 3)];
        short8 af1 = *(short8*)&Hs[(wv * 32 + 16 + mn) * 136 + (c << 5) + (q << 3)];
#pragma unroll
        for (int nt = 0; nt < 8; ++nt) {
            short8 bf = *(short8*)&Bs[(nt * 16 + mn) * 40 + (q << 3)];
            acc2[0][nt] = __builtin_amdgcn_mfma_f32_16x16x32_bf16(af0, bf, acc2[0][nt], 0, 0, 0);
            acc2[1][nt] = __builtin_amdgcn_mfma_f32_16x16x32_bf16(af1, bf, acc2[1][nt], 0, 0, 0);
        }
        __syncthreads();
    }

    // ---- m = acc2 + b2 -> Hs (C-layout, own band; packed converts) ----
#pragma unroll
    for (int h = 0; h < 2; ++h)
#pragma unroll
        for (int nt = 0; nt < 8; ++nt) {
            float b2v = b2[nt * 16 + mn];
#pragma unroll
            for (int rp = 0; rp < 2; ++rp) {
                unsigned int u = pack2(acc2[h][nt][2 * rp] + b2v, acc2[h][nt][2 * rp + 1] + b2v);
                const int row = wv * 32 + h * 16 + q * 4 + 2 * rp;
                Hs[row * 136 + nt * 16 + mn]       = (unsigned short)u;
                Hs[(row + 1) * 136 + nt * 16 + mn] = (unsigned short)(u >> 16);
            }
        }

    // ---- ef_new = ef_old(regs) + m : A-frag order, 64B sectors, no re-read ----
#pragma unroll
    for (int h = 0; h < 2; ++h) {
        const int row = wv * 32 + h * 16 + mn;
        unsigned short* ep_ = ef + (eb + row) * HIDDEN + (q << 3);
#pragma unroll
        for (int c = 0; c < 4; ++c) {
            uint4 mh = *(uint4*)&Hs[row * 136 + (c << 5) + (q << 3)];
            float m[8], e[8];
            unpack8(mh, m);
            short8 eo = h ? efold1[c] : efold0[c];
            uint4 eu = *(uint4*)&eo;
            unpack8(eu, e);
            uint4 nw;
            nw.x = pack2(e[0] + m[0], e[1] + m[1]);
            nw.y = pack2(e[2] + m[2], e[3] + m[3]);
            nw.z = pack2(e[4] + m[4], e[5] + m[5]);
            nw.w = pack2(e[6] + m[6], e[7] + m[7]);
            *(uint4*)(ep_ + (c << 5)) = nw;
        }
    }

    // ---- segmented reduction by dst-run (own band rows, barrier-free) ----
    {
        const int cp = (tid & 63) << 1;
        const int qr = tid >> 6;
        float s0 = 0.0f, s1 = 0.0f;
        int cur = dv[qr * 32];
        for (int r = 0; r < 32; ++r) {
            const int row = qr * 32 + r;
            const int d = dv[row];
            if (d != cur) {
                atomicAdd(&sums[(long)cur * HIDDEN + cp], s0);
                atomicAdd(&sums[(long)cur * HIDDEN + cp + 1], s1);
                s0 = 0.0f; s1 = 0.0f;
                cur = d;
            }
            unsigned int u = *(unsigned int*)&Hs[row * 136 + cp];
            s0 += bf2f((unsigned short)(u & 0xffff));
            s1 += bf2f((unsigned short)(u >> 16));
        }
        atomicAdd(&sums[(long)cur * HIDDEN + cp], s0);
        atomicAdd(&sums[(long)cur * HIDDEN + cp + 1], s1);
    }
}

// ---------------------------------------------------------------------------
// MFMA node layer — r10 exact structure; packed bf16 converts.
// ---------------------------------------------------------------------------
__global__ __launch_bounds__(256, 4)
void node_layer_mfma(float* __restrict__ x,
                     float* __restrict__ sums,
                     const int* __restrict__ deg,
                     const unsigned short* __restrict__ N1T,  // [128][256] bf16
                     const float* __restrict__ b1,
                     const unsigned short* __restrict__ N2T,  // [128][128] bf16
                     const float* __restrict__ b2,
                     const unsigned short* __restrict__ W1Tn, // [128][384] next layer (or null)
                     unsigned short* __restrict__ Xa,
                     unsigned short* __restrict__ Xb)
{
    __shared__ __align__(16) unsigned short As[64 * 40];
    __shared__ __align__(16) unsigned short Bs[128 * 40];
    __shared__ __align__(16) unsigned short Hs[64 * 136];
    __shared__ float cInv[64];

    const int tid = threadIdx.x;
    const long n0 = (long)blockIdx.x * 64;
    if (tid < 64) {
        long n = n0 + tid;
        cInv[tid] = (n < NNODES) ? 1.0f / fmaxf((float)deg[n], 1.0f) : 0.0f;
    }

    const int lane = tid & 63;
    const int wv   = tid >> 6;
    const int mn   = lane & 15;
    const int q    = lane >> 4;
    const int srow = tid >> 2;
    const int sseg = tid & 3;
    const int bn   = tid >> 1;
    const int bk   = (tid & 1) << 4;

    long nr = n0 + srow;
    if (nr >= NNODES) nr = NNODES - 1;

    __syncthreads();

    f32x4 acc[8];
#pragma unroll
    for (int t = 0; t < 8; ++t) acc[t] = (f32x4)0.0f;

    float4 pa0, pa1;
    uint4 pb0, pb1;
    {
        const float* spx = x + nr * HIDDEN + (sseg << 3);
        pa0 = *(const float4*)spx;
        pa1 = *(const float4*)(spx + 4);
        const unsigned short* wp = N1T + (long)bn * 256 + bk;
        pb0 = *(const uint4*)wp;
        pb1 = *(const uint4*)(wp + 8);
    }
    float scCur = 1.0f;
    for (int c = 0; c < 8; ++c) {
        {
            uint4 w;
            w.x = pack2(pa0.x * scCur, pa0.y * scCur); w.y = pack2(pa0.z * scCur, pa0.w * scCur);
            w.z = pack2(pa1.x * scCur, pa1.y * scCur); w.w = pack2(pa1.z * scCur, pa1.w * scCur);
            *(uint4*)&As[srow * 40 + (sseg << 3)] = w;
        }
        *(uint4*)&Bs[bn * 40 + bk]     = pb0;
        *(uint4*)&Bs[bn * 40 + bk + 8] = pb1;
        __syncthreads();
        if (c + 1 < 8) {
            const int cn = c + 1;
            const float* base = (cn < 4) ? x : sums;
            scCur = (cn < 4) ? 1.0f : cInv[srow];
            const float* spx = base + nr * HIDDEN + ((cn & 3) << 5) + (sseg << 3);
            pa0 = *(const float4*)spx;
            pa1 = *(const float4*)(spx + 4);
            const unsigned short* wp = N1T + (long)bn * 256 + (cn << 5) + bk;
            pb0 = *(const uint4*)wp;
            pb1 = *(const uint4*)(wp + 8);
        }
        short8 af = *(short8*)&As[(wv * 16 + mn) * 40 + (q << 3)];
#pragma unroll
        for (int nt = 0; nt < 8; ++nt) {
            short8 bf = *(short8*)&Bs[(nt * 16 + mn) * 40 + (q << 3)];
            acc[nt] = __builtin_amdgcn_mfma_f32_16x16x32_bf16(af, bf, acc[nt], 0, 0, 0);
        }
        __syncthreads();
    }

    // zero own sums rows for the next layer
    {
        long row = n0 + srow;
        if (row < NNODES) {
            float4 z = make_float4(0.f, 0.f, 0.f, 0.f);
            float* p = sums + row * HIDDEN + (sseg << 5);
#pragma unroll
            for (int i = 0; i < 8; ++i) ((float4*)p)[i] = z;
        }
    }

#pragma unroll
    for (int nt = 0; nt < 8; ++nt) {
        float b1v = b1[nt * 16 + mn];
#pragma unroll
        for (int rp = 0; rp < 2; ++rp) {
            float h0 = fmaxf(acc[nt][2 * rp] + b1v, 0.0f);
            float h1 = fmaxf(acc[nt][2 * rp + 1] + b1v, 0.0f);
            unsigned int u = pack2(h0, h1);
            const int row = wv * 16 + q * 4 + 2 * rp;
            Hs[row * 136 + nt * 16 + mn]       = (unsigned short)u;
            Hs[(row + 1) * 136 + nt * 16 + mn] = (unsigned short)(u >> 16);
        }
    }

    f32x4 acc2[8];
#pragma unroll
    for (int t = 0; t < 8; ++t) acc2[t] = (f32x4)0.0f;
    {
        const unsigned short* wp = N2T + (long)bn * 128 + bk;
        pb0 = *(const uint4*)wp;
        pb1 = *(const uint4*)(wp + 8);
    }
    for (int c = 0; c < 4; ++c) {
        *(uint4*)&Bs[bn * 40 + bk]     = pb0;
        *(uint4*)&Bs[bn * 40 + bk + 8] = pb1;
        __syncthreads();
        if (c + 1 < 4) {
            const unsigned short* wp = N2T + (long)bn * 128 + ((c + 1) << 5) + bk;
            pb0 = *(const uint4*)wp;
            pb1 = *(const uint4*)(wp + 8);
        }
        short8 af = *(short8*)&Hs[(wv * 16 + mn) * 136 + (c << 5) + (q << 3)];
#pragma unroll
        for (int nt = 0; nt < 8; ++nt) {
            short8 bf = *(short8*)&Bs[(nt * 16 + mn) * 40 + (q << 3)];
            acc2[nt] = __builtin_amdgcn_mfma_f32_16x16x32_bf16(af, bf, acc2[nt], 0, 0, 0);
        }
        __syncthreads();
    }

    // ---- xnew = x + acc2 + b2 (exact fp32); stage xnew bf16 into Hs ----
#pragma unroll
    for (int nt = 0; nt < 8; ++nt) {
        float b2v = b2[nt * 16 + mn];
        float xn[4];
#pragma unroll
        for (int r = 0; r < 4; ++r) {
            long row = n0 + wv * 16 + q * 4 + r;
            xn[r] = 0.0f;
            if (row < NNODES) {
                float* p = x + row * HIDDEN + nt * 16 + mn;
                xn[r] = *p + acc2[nt][r] + b2v;
                *p = xn[r];
            }
        }
#pragma unroll
        for (int rp = 0; rp < 2; ++rp) {
            unsigned int u = pack2(xn[2 * rp], xn[2 * rp + 1]);
            const int row = wv * 16 + q * 4 + 2 * rp;
            Hs[row * 136 + nt * 16 + mn]       = (unsigned short)u;
            Hs[(row + 1) * 136 + nt * 16 + mn] = (unsigned short)(u >> 16);
        }
    }

    // ---- Xa/Xb for next layer: xnew @ W1a / W1b ----
    if (W1Tn) {
#pragma unroll
        for (int half = 0; half < 2; ++half) {
            f32x4 accN[8];
#pragma unroll
            for (int t = 0; t < 8; ++t) accN[t] = (f32x4)0.0f;
            const int kbase = half << 7;
            {
                const unsigned short* wp = W1Tn + (long)bn * 384 + kbase + bk;
                pb0 = *(const uint4*)wp;
                pb1 = *(const uint4*)(wp + 8);
            }
            for (int c = 0; c < 4; ++c) {
                *(uint4*)&Bs[bn * 40 + bk]     = pb0;
                *(uint4*)&Bs[bn * 40 + bk + 8] = pb1;
                __syncthreads();
                if (c + 1 < 4) {
                    const unsigned short* wp = W1Tn + (long)bn * 384 + kbase + ((c + 1) << 5) + bk;
                    pb0 = *(const uint4*)wp;
                    pb1 = *(const uint4*)(wp + 8);
                }
                short8 af = *(short8*)&Hs[(wv * 16 + mn) * 136 + (c << 5) + (q << 3)];
#pragma unroll
                for (int nt = 0; nt < 8; ++nt) {
                    short8 bf = *(short8*)&Bs[(nt * 16 + mn) * 40 + (q << 3)];
                    accN[nt] = __builtin_amdgcn_mfma_f32_16x16x32_bf16(af, bf, accN[nt], 0, 0, 0);
                }
                __syncthreads();
            }
            unsigned short* Xout = half ? Xb : Xa;
#pragma unroll
            for (int nt = 0; nt < 8; ++nt) {
#pragma unroll
                for (int rp = 0; rp < 2; ++rp) {
                    unsigned int u = pack2(accN[nt][2 * rp], accN[nt][2 * rp + 1]);
                    long row0 = n0 + wv * 16 + q * 4 + 2 * rp;
                    if (row0 < NNODES)     Xout[row0 * HIDDEN + nt * 16 + mn]       = (unsigned short)u;
                    if (row0 + 1 < NNODES) Xout[(row0 + 1) * HIDDEN + nt * 16 + mn] = (unsigned short)(u >> 16);
                }
            }
        }
    }
}

// ---------------------------------------------------------------------------
// Decoder + row L2-normalize (one wave per node)
// ---------------------------------------------------------------------------
__global__ void decode_kernel(const float* __restrict__ x,
                              const float* __restrict__ w,
                              const float* __restrict__ b,
                              float* __restrict__ out)
{
    int gid = blockIdx.x * blockDim.x + threadIdx.x;
    int node = gid >> 6;
    int lane = threadIdx.x & 63;
    if (node >= NNODES) return;
    float a0 = 0.f, a1 = 0.f, a2 = 0.f;
#pragma unroll
    for (int k = lane; k < HIDDEN; k += 64) {
        float xv = x[(long)node * HIDDEN + k];
        a0 = fmaf(xv, w[k * 3 + 0], a0);
        a1 = fmaf(xv, w[k * 3 + 1], a1);
        a2 = fmaf(xv, w[k * 3 + 2], a2);
    }
#pragma unroll
    for (int off = 32; off > 0; off >>= 1) {
        a0 += __shfl_down(a0, off);
        a1 += __shfl_down(a1, off);
        a2 += __shfl_down(a2, off);
    }
    if (lane == 0) {
        a0 += b[0]; a1 += b[1]; a2 += b[2];
        float nrm = sqrtf(a0 * a0 + a1 * a1 + a2 * a2);
        float inv = 1.0f / fmaxf(nrm, 1e-12f);
        out[(long)node * 3 + 0] = a0 * inv;
        out[(long)node * 3 + 1] = a1 * inv;
        out[(long)node * 3 + 2] = a2 * inv;
    }
}

// ---------------------------------------------------------------------------
extern "C" void kernel_launch(void* const* d_in, const int* in_sizes, int n_in,
                              void* d_out, int out_size, void* d_ws, size_t ws_size,
                              hipStream_t stream)
{
    const float* edge_attr = (const float*)d_in[1];
    const int*   ei        = (const int*)d_in[2];
    const float* enc_w     = (const float*)d_in[3];
    const float* enc_b     = (const float*)d_in[4];
    const float* dec_w     = (const float*)d_in[5];
    const float* dec_b     = (const float*)d_in[6];
    const float* edge_w1   = (const float*)d_in[7];
    const float* edge_b1   = (const float*)d_in[8];
    const float* edge_w2   = (const float*)d_in[9];
    const float* edge_b2   = (const float*)d_in[10];
    const float* node_w1   = (const float*)d_in[11];
    const float* node_b1   = (const float*)d_in[12];
    const float* node_w2   = (const float*)d_in[13];
    const float* node_b2   = (const float*)d_in[14];

    // workspace layout (bytes), 16B-aligned, total ~255.4 MB
    char* ws = (char*)d_ws;
    unsigned short* ef  = (unsigned short*)(ws);                  // 163,840,000
    float* x      = (float*)(ws + 163840000L);                    //  25,600,000
    float* sums   = (float*)(ws + 189440000L);                    //  25,600,000
    int*   src32  = (int*)  (ws + 215040000L);                    //   2,560,000
    int*   dst32  = (int*)  (ws + 217600000L);                    //   2,560,000
    int*   sp     = (int*)  (ws + 220160000L);                    //   2,560,000
    int*   dp     = (int*)  (ws + 222720000L);                    //   2,560,000
    int*   eperm  = (int*)  (ws + 225280000L);                    //   2,560,000
    int*   deg    = (int*)  (ws + 227840000L);                    //     200,704
    int*   off    = (int*)  (ws + 228040704L);                    //     200,704
    int*   cursor = (int*)  (ws + 228241408L);                    //     200,704
    int*   flag   = (int*)  (ws + 228442112L);                    //          64
    unsigned short* W1T = (unsigned short*)(ws + 228442176L);     //     589,824
    unsigned short* W2T = (unsigned short*)(ws + 229032000L);     //     196,608
    unsigned short* N1T = (unsigned short*)(ws + 229228608L);     //     393,216
    unsigned short* N2T = (unsigned short*)(ws + 229621824L);     //     196,608
    unsigned short* Xa  = (unsigned short*)(ws + 229818432L);     //  12,800,000
    unsigned short* Xb  = (unsigned short*)(ws + 242618432L);     //  12,800,000
    // end: 255,418,432

    float* out = (float*)d_out;

    hipMemsetAsync(x, 0, (size_t)NNODES * HIDDEN * sizeof(float), stream);
    hipMemsetAsync(sums, 0, (size_t)NNODES * HIDDEN * sizeof(float), stream);
    hipMemsetAsync(deg, 0, 200704, stream);
    hipMemsetAsync(Xa, 0, 25600000, stream);   // Xa + Xb (contiguous)

    detect_kernel<<<1, 64, 0, stream>>>(ei, flag);
    normidx_kernel<<<(NEDGES + 255) / 256, 256, 0, stream>>>(ei, flag, src32, dst32);
    degree_kernel<<<(NEDGES + 255) / 256, 256, 0, stream>>>(dst32, deg);
    scan_kernel<<<1, SCAN_T, 0, stream>>>(deg, off, cursor);
    scatter_kernel<<<(NEDGES + 255) / 256, 256, 0, stream>>>(src32, dst32, cursor, sp, dp, eperm);
    encode_kernel<<<(NEDGES * 32 + 255) / 256, 256, 0, stream>>>(edge_attr, enc_w, enc_b, eperm, ef);

    transpose_kernel<<<(6 * 384 * 128 + 255) / 256, 256, 0, stream>>>(edge_w1, W1T, 384, 128, 6);
    transpose_kernel<<<(6 * 128 * 128 + 255) / 256, 256, 0, stream>>>(edge_w2, W2T, 128, 128, 6);
    transpose_kernel<<<(6 * 256 * 128 + 255) / 256, 256, 0, stream>>>(node_w1, N1T, 256, 128, 6);
    transpose_kernel<<<(6 * 128 * 128 + 255) / 256, 256, 0, stream>>>(node_w2, N2T, 128, 128, 6);

    for (int l = 0; l < NLAYERS; ++l) {
        edge_layer_mfma<<<NEDGES / 128, 256, 0, stream>>>(
            Xa, Xb, ef, sums, sp, dp,
            W1T + (long)l * 384 * 128, edge_b1 + (long)l * HIDDEN,
            W2T + (long)l * 128 * 128, edge_b2 + (long)l * HIDDEN);
        const unsigned short* w1next = (l + 1 < NLAYERS) ? (W1T + (long)(l + 1) * 384 * 128) : nullptr;
        node_layer_mfma<<<(NNODES + 63) / 64, 256, 0, stream>>>(
            x, sums, deg,
            N1T + (long)l * 256 * 128, node_b1 + (long)l * HIDDEN,
            N2T + (long)l * 128 * 128, node_b2 + (long)l * HIDDEN,
            w1next, Xa, Xb);
    }

    decode_kernel<<<(NNODES * 64 + 255) / 256, 256, 0, stream>>>(x, dec_w, dec_b, out);
}

// Round 14
// 1554.304 us; speedup vs baseline: 1.0806x; 1.0021x over previous
//
#include <hip/hip_runtime.h>
#include <cstdint>

#define HIDDEN  128
#define NLAYERS 6
#define NNODES  50000
#define NEDGES  640000

typedef short short8 __attribute__((ext_vector_type(8)));
typedef float f32x4  __attribute__((ext_vector_type(4)));

// ---- bf16 <-> f32 helpers (RNE) -------------------------------------------
__device__ __forceinline__ float bf2f(unsigned short u) {
    return __uint_as_float(((unsigned int)u) << 16);
}
__device__ __forceinline__ unsigned short f2bf(float f) {
    unsigned int u = __float_as_uint(f);
    unsigned int r = u + 0x7FFFu + ((u >> 16) & 1u);
    return (unsigned short)(r >> 16);
}
__device__ __forceinline__ unsigned int pack2(float a, float b) {
    return (unsigned int)f2bf(a) | ((unsigned int)f2bf(b) << 16);
}
__device__ __forceinline__ void unpack8(uint4 v, float* f) {
    f[0] = bf2f((unsigned short)(v.x & 0xffff)); f[1] = bf2f((unsigned short)(v.x >> 16));
    f[2] = bf2f((unsigned short)(v.y & 0xffff)); f[3] = bf2f((unsigned short)(v.y >> 16));
    f[4] = bf2f((unsigned short)(v.z & 0xffff)); f[5] = bf2f((unsigned short)(v.z >> 16));
    f[6] = bf2f((unsigned short)(v.w & 0xffff)); f[7] = bf2f((unsigned short)(v.w >> 16));
}

// ---------------------------------------------------------------------------
// Index dtype detection + canonicalization
// ---------------------------------------------------------------------------
__global__ void detect_kernel(const int* __restrict__ ei, int* __restrict__ flag)
{
    int lane = threadIdx.x;
    int v = ei[2 * lane + 1];
    unsigned long long b = __ballot(v != 0);
    if (lane == 0) *flag = (b != 0ULL) ? 1 : 0;
}

__global__ void normidx_kernel(const int* __restrict__ ei, const int* __restrict__ flag,
                               int* __restrict__ s32, int* __restrict__ d32)
{
    int e = blockIdx.x * blockDim.x + threadIdx.x;
    if (e >= NEDGES) return;
    int s, d;
    if (*flag) { s = ei[e]; d = ei[NEDGES + e]; }
    else       { s = ei[2 * e]; d = ei[2 * (NEDGES + e)]; }
    s32[e] = min(max(s, 0), NNODES - 1);
    d32[e] = min(max(d, 0), NNODES - 1);
}

__global__ void degree_kernel(const int* __restrict__ dst, int* __restrict__ deg)
{
    int e = blockIdx.x * blockDim.x + threadIdx.x;
    if (e < NEDGES) atomicAdd(&deg[dst[e]], 1);
}

// ---------------------------------------------------------------------------
// Exclusive scan over deg[0..NNODES) -> off, cursor. One 1024-thread block.
// ---------------------------------------------------------------------------
#define SCAN_T 1024
__global__ void scan_kernel(const int* __restrict__ deg, int* __restrict__ off,
                            int* __restrict__ cursor)
{
    __shared__ int part[SCAN_T];
    const int t = threadIdx.x;
    const int CH = (NNODES + SCAN_T - 1) / SCAN_T;
    const int base = t * CH;
    int s = 0;
    for (int i = 0; i < CH; ++i) {
        int idx = base + i;
        if (idx < NNODES) s += deg[idx];
    }
    part[t] = s;
    __syncthreads();
    for (int d = 1; d < SCAN_T; d <<= 1) {
        int v = (t >= d) ? part[t - d] : 0;
        __syncthreads();
        part[t] += v;
        __syncthreads();
    }
    int run = (t == 0) ? 0 : part[t - 1];
    for (int i = 0; i < CH; ++i) {
        int idx = base + i;
        if (idx < NNODES) {
            off[idx] = run;
            cursor[idx] = run;
            run += deg[idx];
        }
    }
    if (t == SCAN_T - 1) off[NNODES] = run;
}

__global__ void scatter_kernel(const int* __restrict__ s32, const int* __restrict__ d32,
                               int* __restrict__ cursor,
                               int* __restrict__ sp, int* __restrict__ dp, int* __restrict__ ep)
{
    int e = blockIdx.x * blockDim.x + threadIdx.x;
    if (e >= NEDGES) return;
    int d = d32[e];
    int p = atomicAdd(&cursor[d], 1);
    sp[p] = s32[e];
    dp[p] = d;
    ep[p] = e;
}

// ---------------------------------------------------------------------------
// Weight transpose+convert: W [L][K][N] fp32 -> WT [L][N][K] bf16
// ---------------------------------------------------------------------------
__global__ void transpose_kernel(const float* __restrict__ W, unsigned short* __restrict__ WT,
                                 int K, int N, int L)
{
    long idx = (long)blockIdx.x * 256 + threadIdx.x;
    long tot = (long)L * K * N;
    if (idx >= tot) return;
    int kn = (int)(idx % ((long)K * N));
    int l  = (int)(idx / ((long)K * N));
    int k = kn / N;
    int n = kn % N;
    WT[(long)l * K * N + (long)n * K + k] = f2bf(W[idx]);
}

// ---------------------------------------------------------------------------
// Encoder into permuted layout: ef[p] = enc(ea[ep[p]])
// ---------------------------------------------------------------------------
__global__ void encode_kernel(const float* __restrict__ ea,
                              const float* __restrict__ w,
                              const float* __restrict__ b,
                              const int* __restrict__ ep,
                              unsigned short* __restrict__ ef)
{
    int idx = blockIdx.x * blockDim.x + threadIdx.x;
    int p = idx >> 5;
    if (p >= NEDGES) return;
    int e = ep[p];
    int j = (idx & 31) << 2;
    float a0 = ea[e * 3 + 0], a1 = ea[e * 3 + 1], a2 = ea[e * 3 + 2];
    float4 w0 = *(const float4*)(w + 0 * HIDDEN + j);
    float4 w1 = *(const float4*)(w + 1 * HIDDEN + j);
    float4 w2 = *(const float4*)(w + 2 * HIDDEN + j);
    float4 bb = *(const float4*)(b + j);
    ushort4 o;
    o.x = f2bf(fmaf(a0, w0.x, fmaf(a1, w1.x, fmaf(a2, w2.x, bb.x))));
    o.y = f2bf(fmaf(a0, w0.y, fmaf(a1, w1.y, fmaf(a2, w2.y, bb.y))));
    o.z = f2bf(fmaf(a0, w0.z, fmaf(a1, w1.z, fmaf(a2, w2.z, bb.z))));
    o.w = f2bf(fmaf(a0, w0.w, fmaf(a1, w1.w, fmaf(a2, w2.w, bb.w))));
    *(ushort4*)(ef + (long)p * HIDDEN + j) = o;
}

// ---------------------------------------------------------------------------
// MFMA edge layer — r10 tile/barrier structure, 8 waves (512 thr), 16 rows/wave.
// Same LDS (3 blocks/CU) but 24 waves/CU resident (2x r10). All post-GEMM1
// phases wave-private under 16-row bands.
// ---------------------------------------------------------------------------
__global__ __launch_bounds__(512, 6)
void edge_layer_mfma(const unsigned short* __restrict__ Xa,   // [N][128] bf16
                     const unsigned short* __restrict__ Xb,   // [N][128] bf16
                     unsigned short* __restrict__ ef,
                     float* __restrict__ sums,
                     const int* __restrict__ sp,
                     const int* __restrict__ dp,
                     const unsigned short* __restrict__ W1T,  // [128][384] bf16; W1c at k+256
                     const float* __restrict__ b1,
                     const unsigned short* __restrict__ W2T,  // [128][128] bf16
                     const float* __restrict__ b2)
{
    // 0      .. 34816 : Hs (128 x 136) / As (128 x 40) aliased
    // 34816  .. 45056 : Bs (128 x 40)
    __shared__ __align__(16) unsigned char buf[45056];
    unsigned short* As = (unsigned short*)buf;
    unsigned short* Hs = (unsigned short*)buf;
    unsigned short* Bs = (unsigned short*)(buf + 34816);
    __shared__ int dv[128];
    __shared__ int sv[128];

    const int tid = threadIdx.x;
    const long eb = (long)blockIdx.x * 128;
    if (tid < 128)       dv[tid]       = dp[eb + tid];
    else if (tid < 256)  sv[tid - 128] = sp[eb + tid - 128];

    const int lane = tid & 63;
    const int wv   = tid >> 6;          // 0..7, wave owns rows [wv*16, wv*16+16)
    const int mn   = lane & 15;
    const int q    = lane >> 4;
    const int rr   = tid >> 2;          // staging row 0..127
    const int o    = (tid & 3) << 3;    // 8-short quarter of 32-k chunk
    const int bn   = tid >> 2;          // Bs row 0..127
    const int bo   = (tid & 3) << 3;

    f32x4 acc[8];
#pragma unroll
    for (int t = 0; t < 8; ++t) acc[t] = (f32x4)0.0f;

    short8 efold[4];                    // ef_old A-fragments (16 VGPRs)

    uint4 pa, pw;
    {   // chunk 0 loads
        pa = *(const uint4*)(ef + (eb + rr) * HIDDEN + o);
        pw = *(const uint4*)(W1T + (long)bn * 384 + 256 + bo);
    }

    // ---- GEMM1: ef @ W1c, 4 k-steps of 32, register-prefetched ----
    for (int c = 0; c < 4; ++c) {
        *(uint4*)&As[rr * 40 + o]  = pa;
        *(uint4*)&Bs[bn * 40 + bo] = pw;
        __syncthreads();

        if (c + 1 < 4) {
            const int cn = c + 1;
            pa = *(const uint4*)(ef + (eb + rr) * HIDDEN + (cn << 5) + o);
            pw = *(const uint4*)(W1T + (long)bn * 384 + 256 + (cn << 5) + bo);
        }

        short8 af = *(short8*)&As[(wv * 16 + mn) * 40 + (q << 3)];
        efold[c] = af;
#pragma unroll
        for (int nt = 0; nt < 8; ++nt) {
            short8 bf = *(short8*)&Bs[(nt * 16 + mn) * 40 + (q << 3)];
            acc[nt] = __builtin_amdgcn_mfma_f32_16x16x32_bf16(af, bf, acc[nt], 0, 0, 0);
        }
        __syncthreads();
    }
    // All As reads done (final barrier above) -> Hs alias safe.

    // ---- pre -> Hs (C-layout, own wave band; no barrier needed after) ----
#pragma unroll
    for (int nt = 0; nt < 8; ++nt)
#pragma unroll
        for (int r = 0; r < 4; ++r)
            Hs[(wv * 16 + q * 4 + r) * 136 + nt * 16 + mn] = f2bf(acc[nt][r]);

    // ---- H = relu(pre + Xa[dst] + Xb[src] + b1), row-major vector gather ----
    // lane -> row = wv*16 + (lane>>2), col quarter = (lane&3)*32 : own band.
    {
        const int row = wv * 16 + (lane >> 2);
        const int ch  = (lane & 3) << 5;
        const unsigned short* xap = Xa + (long)dv[row] * HIDDEN + ch;
        const unsigned short* xbp = Xb + (long)sv[row] * HIDDEN + ch;
        unsigned short* hp = &Hs[row * 136 + ch];
#pragma unroll
        for (int i = 0; i < 4; ++i) {
            uint4 va = *(const uint4*)(xap + (i << 3));
            uint4 vb = *(const uint4*)(xbp + (i << 3));
            uint4 vp = *(uint4*)(hp + (i << 3));
            float fa[8], fb[8], fp[8];
            unpack8(va, fa); unpack8(vb, fb); unpack8(vp, fp);
            const float* bp = b1 + ch + (i << 3);
            uint4 nw;
            float h0 = fmaxf(fp[0] + fa[0] + fb[0] + bp[0], 0.0f);
            float h1 = fmaxf(fp[1] + fa[1] + fb[1] + bp[1], 0.0f);
            float h2 = fmaxf(fp[2] + fa[2] + fb[2] + bp[2], 0.0f);
            float h3 = fmaxf(fp[3] + fa[3] + fb[3] + bp[3], 0.0f);
            float h4 = fmaxf(fp[4] + fa[4] + fb[4] + bp[4], 0.0f);
            float h5 = fmaxf(fp[5] + fa[5] + fb[5] + bp[5], 0.0f);
            float h6 = fmaxf(fp[6] + fa[6] + fb[6] + bp[6], 0.0f);
            float h7 = fmaxf(fp[7] + fa[7] + fb[7] + bp[7], 0.0f);
            nw.x = pack2(h0, h1); nw.y = pack2(h2, h3);
            nw.z = pack2(h4, h5); nw.w = pack2(h6, h7);
            *(uint4*)(hp + (i << 3)) = nw;
        }
    }
    // No barrier: GEMM2 A-frags read only this wave's band (DS wave-ordered).

    // ---- GEMM2: H @ W2, 4 k-steps, Bs staged + prefetched ----
    f32x4 acc2[8];
#pragma unroll
    for (int t = 0; t < 8; ++t) acc2[t] = (f32x4)0.0f;
    {
        pw = *(const uint4*)(W2T + (long)bn * 128 + bo);
    }
    for (int c = 0; c < 4; ++c) {
        *(uint4*)&Bs[bn * 40 + bo] = pw;
        __syncthreads();
        if (c + 1 < 4) {
            pw = *(const uint4*)(W2T + (long)bn * 128 + ((c + 1) << 5) + bo);
        }
        short8 af = *(short8*)&Hs[(wv * 16 + mn) * 136 + (c << 5) + (q << 3)];
#pragma unroll
        for (int nt = 0; nt < 8; ++nt) {
            short8 bf = *(short8*)&Bs[(nt * 16 + mn) * 40 + (q << 3)];
            acc2[nt] = __builtin_amdgcn_mfma_f32_16x16x32_bf16(af, bf, acc2[nt], 0, 0, 0);
        }
        __syncthreads();
    }

    // ---- m = acc2 + b2 -> Hs (C-layout, own band) ----
#pragma unroll
    for (int nt = 0; nt < 8; ++nt) {
        float b2v = b2[nt * 16 + mn];
#pragma unroll
        for (int r = 0; r < 4; ++r)
            Hs[(wv * 16 + q * 4 + r) * 136 + nt * 16 + mn] = f2bf(acc2[nt][r] + b2v);
    }

    // ---- ef_new = ef_old(regs) + m : A-frag order, no re-read ----
    {
        const int row = wv * 16 + mn;
        unsigned short* ep_ = ef + (eb + row) * HIDDEN + (q << 3);
#pragma unroll
        for (int c = 0; c < 4; ++c) {
            uint4 mh = *(uint4*)&Hs[row * 136 + (c << 5) + (q << 3)];
            float m[8], e[8];
            unpack8(mh, m);
            uint4 eu = *(uint4*)&efold[c];
            unpack8(eu, e);
            uint4 nw;
            nw.x = pack2(e[0] + m[0], e[1] + m[1]);
            nw.y = pack2(e[2] + m[2], e[3] + m[3]);
            nw.z = pack2(e[4] + m[4], e[5] + m[5]);
            nw.w = pack2(e[6] + m[6], e[7] + m[7]);
            *(uint4*)(ep_ + (c << 5)) = nw;
        }
    }

    // ---- segmented reduction by dst-run (own 16-row strip, barrier-free) ----
    {
        const int cp = lane << 1;           // column pair
        float s0 = 0.0f, s1 = 0.0f;
        int cur = dv[wv * 16];
        for (int r = 0; r < 16; ++r) {
            const int row = wv * 16 + r;
            const int d = dv[row];
            if (d != cur) {
                atomicAdd(&sums[(long)cur * HIDDEN + cp], s0);
                atomicAdd(&sums[(long)cur * HIDDEN + cp + 1], s1);
                s0 = 0.0f; s1 = 0.0f;
                cur = d;
            }
            unsigned int u = *(unsigned int*)&Hs[row * 136 + cp];
            s0 += bf2f((unsigned short)(u & 0xffff));
            s1 += bf2f((unsigned short)(u >> 16));
        }
        atomicAdd(&sums[(long)cur * HIDDEN + cp], s0);
        atomicAdd(&sums[(long)cur * HIDDEN + cp + 1], s1);
    }
}

// ---------------------------------------------------------------------------
// MFMA node layer — r10 structure + As-under-Hs LDS aliasing (27.9 KB ->
// 5 blocks/CU). Otherwise identical.
// ---------------------------------------------------------------------------
__global__ __launch_bounds__(256, 5)
void node_layer_mfma(float* __restrict__ x,
                     float* __restrict__ sums,
                     const int* __restrict__ deg,
                     const unsigned short* __restrict__ N1T,  // [128][256] bf16
                     const float* __restrict__ b1,
                     const unsigned short* __restrict__ N2T,  // [128][128] bf16
                     const float* __restrict__ b2,
                     const unsigned short* __restrict__ W1Tn, // [128][384] next layer (or null)
                     unsigned short* __restrict__ Xa,
                     unsigned short* __restrict__ Xb)
{
    // 0     .. 17408 : Hs (64 x 136) / As (64 x 40) aliased
    // 17408 .. 27648 : Bs (128 x 40)
    __shared__ __align__(16) unsigned char nbuf[27648];
    unsigned short* As = (unsigned short*)nbuf;
    unsigned short* Hs = (unsigned short*)nbuf;
    unsigned short* Bs = (unsigned short*)(nbuf + 17408);
    __shared__ float cInv[64];

    const int tid = threadIdx.x;
    const long n0 = (long)blockIdx.x * 64;
    if (tid < 64) {
        long n = n0 + tid;
        cInv[tid] = (n < NNODES) ? 1.0f / fmaxf((float)deg[n], 1.0f) : 0.0f;
    }

    const int lane = tid & 63;
    const int wv   = tid >> 6;
    const int mn   = lane & 15;
    const int q    = lane >> 4;
    const int srow = tid >> 2;
    const int sseg = tid & 3;
    const int bn   = tid >> 1;
    const int bk   = (tid & 1) << 4;

    long nr = n0 + srow;
    if (nr >= NNODES) nr = NNODES - 1;

    __syncthreads();

    f32x4 acc[8];
#pragma unroll
    for (int t = 0; t < 8; ++t) acc[t] = (f32x4)0.0f;

    float4 pa0, pa1;
    uint4 pb0, pb1;
    {
        const float* spx = x + nr * HIDDEN + (sseg << 3);
        pa0 = *(const float4*)spx;
        pa1 = *(const float4*)(spx + 4);
        const unsigned short* wp = N1T + (long)bn * 256 + bk;
        pb0 = *(const uint4*)wp;
        pb1 = *(const uint4*)(wp + 8);
    }
    float scCur = 1.0f;
    for (int c = 0; c < 8; ++c) {
        {
            uint4 w;
            w.x = pack2(pa0.x * scCur, pa0.y * scCur); w.y = pack2(pa0.z * scCur, pa0.w * scCur);
            w.z = pack2(pa1.x * scCur, pa1.y * scCur); w.w = pack2(pa1.z * scCur, pa1.w * scCur);
            *(uint4*)&As[srow * 40 + (sseg << 3)] = w;
        }
        *(uint4*)&Bs[bn * 40 + bk]     = pb0;
        *(uint4*)&Bs[bn * 40 + bk + 8] = pb1;
        __syncthreads();
        if (c + 1 < 8) {
            const int cn = c + 1;
            const float* base = (cn < 4) ? x : sums;
            scCur = (cn < 4) ? 1.0f : cInv[srow];
            const float* spx = base + nr * HIDDEN + ((cn & 3) << 5) + (sseg << 3);
            pa0 = *(const float4*)spx;
            pa1 = *(const float4*)(spx + 4);
            const unsigned short* wp = N1T + (long)bn * 256 + (cn << 5) + bk;
            pb0 = *(const uint4*)wp;
            pb1 = *(const uint4*)(wp + 8);
        }
        short8 af = *(short8*)&As[(wv * 16 + mn) * 40 + (q << 3)];
#pragma unroll
        for (int nt = 0; nt < 8; ++nt) {
            short8 bf = *(short8*)&Bs[(nt * 16 + mn) * 40 + (q << 3)];
            acc[nt] = __builtin_amdgcn_mfma_f32_16x16x32_bf16(af, bf, acc[nt], 0, 0, 0);
        }
        __syncthreads();
    }
    // As reads done (final barrier above) -> Hs alias safe.

    // zero own sums rows for the next layer
    {
        long row = n0 + srow;
        if (row < NNODES) {
            float4 z = make_float4(0.f, 0.f, 0.f, 0.f);
            float* p = sums + row * HIDDEN + (sseg << 5);
#pragma unroll
            for (int i = 0; i < 8; ++i) ((float4*)p)[i] = z;
        }
    }

#pragma unroll
    for (int nt = 0; nt < 8; ++nt) {
        float b1v = b1[nt * 16 + mn];
#pragma unroll
        for (int r = 0; r < 4; ++r) {
            float hv = fmaxf(acc[nt][r] + b1v, 0.0f);
            Hs[(wv * 16 + q * 4 + r) * 136 + nt * 16 + mn] = f2bf(hv);
        }
    }

    f32x4 acc2[8];
#pragma unroll
    for (int t = 0; t < 8; ++t) acc2[t] = (f32x4)0.0f;
    {
        const unsigned short* wp = N2T + (long)bn * 128 + bk;
        pb0 = *(const uint4*)wp;
        pb1 = *(const uint4*)(wp + 8);
    }
    for (int c = 0; c < 4; ++c) {
        *(uint4*)&Bs[bn * 40 + bk]     = pb0;
        *(uint4*)&Bs[bn * 40 + bk + 8] = pb1;
        __syncthreads();
        if (c + 1 < 4) {
            const unsigned short* wp = N2T + (long)bn * 128 + ((c + 1) << 5) + bk;
            pb0 = *(const uint4*)wp;
            pb1 = *(const uint4*)(wp + 8);
        }
        short8 af = *(short8*)&Hs[(wv * 16 + mn) * 136 + (c << 5) + (q << 3)];
#pragma unroll
        for (int nt = 0; nt < 8; ++nt) {
            short8 bf = *(short8*)&Bs[(nt * 16 + mn) * 40 + (q << 3)];
            acc2[nt] = __builtin_amdgcn_mfma_f32_16x16x32_bf16(af, bf, acc2[nt], 0, 0, 0);
        }
        __syncthreads();
    }

    // ---- xnew = x + acc2 + b2 (exact fp32); stage xnew bf16 into Hs ----
#pragma unroll
    for (int nt = 0; nt < 8; ++nt) {
        float b2v = b2[nt * 16 + mn];
#pragma unroll
        for (int r = 0; r < 4; ++r) {
            long row = n0 + wv * 16 + q * 4 + r;
            float xn = 0.0f;
            if (row < NNODES) {
                float* p = x + row * HIDDEN + nt * 16 + mn;
                xn = *p + acc2[nt][r] + b2v;
                *p = xn;
            }
            Hs[(wv * 16 + q * 4 + r) * 136 + nt * 16 + mn] = f2bf(xn);
        }
    }

    // ---- Xa/Xb for next layer: xnew @ W1a / W1b ----
    if (W1Tn) {
#pragma unroll
        for (int half = 0; half < 2; ++half) {
            f32x4 accN[8];
#pragma unroll
            for (int t = 0; t < 8; ++t) accN[t] = (f32x4)0.0f;
            const int kbase = half << 7;
            {
                const unsigned short* wp = W1Tn + (long)bn * 384 + kbase + bk;
                pb0 = *(const uint4*)wp;
                pb1 = *(const uint4*)(wp + 8);
            }
            for (int c = 0; c < 4; ++c) {
                *(uint4*)&Bs[bn * 40 + bk]     = pb0;
                *(uint4*)&Bs[bn * 40 + bk + 8] = pb1;
                __syncthreads();
                if (c + 1 < 4) {
                    const unsigned short* wp = W1Tn + (long)bn * 384 + kbase + ((c + 1) << 5) + bk;
                    pb0 = *(const uint4*)wp;
                    pb1 = *(const uint4*)(wp + 8);
                }
                short8 af = *(short8*)&Hs[(wv * 16 + mn) * 136 + (c << 5) + (q << 3)];
#pragma unroll
                for (int nt = 0; nt < 8; ++nt) {
                    short8 bf = *(short8*)&Bs[(nt * 16 + mn) * 40 + (q << 3)];
                    accN[nt] = __builtin_amdgcn_mfma_f32_16x16x32_bf16(af, bf, accN[nt], 0, 0, 0);
                }
                __syncthreads();
            }
            unsigned short* Xout = half ? Xb : Xa;
#pragma unroll
            for (int nt = 0; nt < 8; ++nt) {
#pragma unroll
                for (int r = 0; r < 4; ++r) {
                    long row = n0 + wv * 16 + q * 4 + r;
                    if (row < NNODES) {
                        Xout[row * HIDDEN + nt * 16 + mn] = f2bf(accN[nt][r]);
                    }
                }
            }
        }
    }
}

// ---------------------------------------------------------------------------
// Decoder + row L2-normalize (one wave per node)
// ---------------------------------------------------------------------------
__global__ void decode_kernel(const float* __restrict__ x,
                              const float* __restrict__ w,
                              const float* __restrict__ b,
                              float* __restrict__ out)
{
    int gid = blockIdx.x * blockDim.x + threadIdx.x;
    int node = gid >> 6;
    int lane = threadIdx.x & 63;
    if (node >= NNODES) return;
    float a0 = 0.f, a1 = 0.f, a2 = 0.f;
#pragma unroll
    for (int k = lane; k < HIDDEN; k += 64) {
        float xv = x[(long)node * HIDDEN + k];
        a0 = fmaf(xv, w[k * 3 + 0], a0);
        a1 = fmaf(xv, w[k * 3 + 1], a1);
        a2 = fmaf(xv, w[k * 3 + 2], a2);
    }
#pragma unroll
    for (int off = 32; off > 0; off >>= 1) {
        a0 += __shfl_down(a0, off);
        a1 += __shfl_down(a1, off);
        a2 += __shfl_down(a2, off);
    }
    if (lane == 0) {
        a0 += b[0]; a1 += b[1]; a2 += b[2];
        float nrm = sqrtf(a0 * a0 + a1 * a1 + a2 * a2);
        float inv = 1.0f / fmaxf(nrm, 1e-12f);
        out[(long)node * 3 + 0] = a0 * inv;
        out[(long)node * 3 + 1] = a1 * inv;
        out[(long)node * 3 + 2] = a2 * inv;
    }
}

// ---------------------------------------------------------------------------
extern "C" void kernel_launch(void* const* d_in, const int* in_sizes, int n_in,
                              void* d_out, int out_size, void* d_ws, size_t ws_size,
                              hipStream_t stream)
{
    const float* edge_attr = (const float*)d_in[1];
    const int*   ei        = (const int*)d_in[2];
    const float* enc_w     = (const float*)d_in[3];
    const float* enc_b     = (const float*)d_in[4];
    const float* dec_w     = (const float*)d_in[5];
    const float* dec_b     = (const float*)d_in[6];
    const float* edge_w1   = (const float*)d_in[7];
    const float* edge_b1   = (const float*)d_in[8];
    const float* edge_w2   = (const float*)d_in[9];
    const float* edge_b2   = (const float*)d_in[10];
    const float* node_w1   = (const float*)d_in[11];
    const float* node_b1   = (const float*)d_in[12];
    const float* node_w2   = (const float*)d_in[13];
    const float* node_b2   = (const float*)d_in[14];

    // workspace layout (bytes), 16B-aligned, total ~255.4 MB
    char* ws = (char*)d_ws;
    unsigned short* ef  = (unsigned short*)(ws);                  // 163,840,000
    float* x      = (float*)(ws + 163840000L);                    //  25,600,000
    float* sums   = (float*)(ws + 189440000L);                    //  25,600,000
    int*   src32  = (int*)  (ws + 215040000L);                    //   2,560,000
    int*   dst32  = (int*)  (ws + 217600000L);                    //   2,560,000
    int*   sp     = (int*)  (ws + 220160000L);                    //   2,560,000
    int*   dp     = (int*)  (ws + 222720000L);                    //   2,560,000
    int*   eperm  = (int*)  (ws + 225280000L);                    //   2,560,000
    int*   deg    = (int*)  (ws + 227840000L);                    //     200,704
    int*   off    = (int*)  (ws + 228040704L);                    //     200,704
    int*   cursor = (int*)  (ws + 228241408L);                    //     200,704
    int*   flag   = (int*)  (ws + 228442112L);                    //          64
    unsigned short* W1T = (unsigned short*)(ws + 228442176L);     //     589,824
    unsigned short* W2T = (unsigned short*)(ws + 229032000L);     //     196,608
    unsigned short* N1T = (unsigned short*)(ws + 229228608L);     //     393,216
    unsigned short* N2T = (unsigned short*)(ws + 229621824L);     //     196,608
    unsigned short* Xa  = (unsigned short*)(ws + 229818432L);     //  12,800,000
    unsigned short* Xb  = (unsigned short*)(ws + 242618432L);     //  12,800,000
    // end: 255,418,432

    float* out = (float*)d_out;

    hipMemsetAsync(x, 0, (size_t)NNODES * HIDDEN * sizeof(float), stream);
    hipMemsetAsync(sums, 0, (size_t)NNODES * HIDDEN * sizeof(float), stream);
    hipMemsetAsync(deg, 0, 200704, stream);
    hipMemsetAsync(Xa, 0, 25600000, stream);   // Xa + Xb (contiguous)

    detect_kernel<<<1, 64, 0, stream>>>(ei, flag);
    normidx_kernel<<<(NEDGES + 255) / 256, 256, 0, stream>>>(ei, flag, src32, dst32);
    degree_kernel<<<(NEDGES + 255) / 256, 256, 0, stream>>>(dst32, deg);
    scan_kernel<<<1, SCAN_T, 0, stream>>>(deg, off, cursor);
    scatter_kernel<<<(NEDGES + 255) / 256, 256, 0, stream>>>(src32, dst32, cursor, sp, dp, eperm);
    encode_kernel<<<(NEDGES * 32 + 255) / 256, 256, 0, stream>>>(edge_attr, enc_w, enc_b, eperm, ef);

    transpose_kernel<<<(6 * 384 * 128 + 255) / 256, 256, 0, stream>>>(edge_w1, W1T, 384, 128, 6);
    transpose_kernel<<<(6 * 128 * 128 + 255) / 256, 256, 0, stream>>>(edge_w2, W2T, 128, 128, 6);
    transpose_kernel<<<(6 * 256 * 128 + 255) / 256, 256, 0, stream>>>(node_w1, N1T, 256, 128, 6);
    transpose_kernel<<<(6 * 128 * 128 + 255) / 256, 256, 0, stream>>>(node_w2, N2T, 128, 128, 6);

    for (int l = 0; l < NLAYERS; ++l) {
        edge_layer_mfma<<<NEDGES / 128, 512, 0, stream>>>(
            Xa, Xb, ef, sums, sp, dp,
            W1T + (long)l * 384 * 128, edge_b1 + (long)l * HIDDEN,
            W2T + (long)l * 128 * 128, edge_b2 + (long)l * HIDDEN);
        const unsigned short* w1next = (l + 1 < NLAYERS) ? (W1T + (long)(l + 1) * 384 * 128) : nullptr;
        node_layer_mfma<<<(NNODES + 63) / 64, 256, 0, stream>>>(
            x, sums, deg,
            N1T + (long)l * 256 * 128, node_b1 + (long)l * HIDDEN,
            N2T + (long)l * 128 * 128, node_b2 + (long)l * HIDDEN,
            w1next, Xa, Xb);
    }

    decode_kernel<<<(NNODES * 64 + 255) / 256, 256, 0, stream>>>(x, dec_w, dec_b, out);
}

// Round 15
// 1541.639 us; speedup vs baseline: 1.0895x; 1.0082x over previous
//
#include <hip/hip_runtime.h>
#include <cstdint>

#define HIDDEN  128
#define NLAYERS 6
#define NNODES  50000
#define NEDGES  640000

typedef short short8 __attribute__((ext_vector_type(8)));
typedef float f32x4  __attribute__((ext_vector_type(4)));

// ---- bf16 <-> f32 helpers (RNE) -------------------------------------------
__device__ __forceinline__ float bf2f(unsigned short u) {
    return __uint_as_float(((unsigned int)u) << 16);
}
__device__ __forceinline__ unsigned short f2bf(float f) {
    unsigned int u = __float_as_uint(f);
    unsigned int r = u + 0x7FFFu + ((u >> 16) & 1u);
    return (unsigned short)(r >> 16);
}
__device__ __forceinline__ unsigned int pack2(float a, float b) {
    return (unsigned int)f2bf(a) | ((unsigned int)f2bf(b) << 16);
}
__device__ __forceinline__ void unpack8(uint4 v, float* f) {
    f[0] = bf2f((unsigned short)(v.x & 0xffff)); f[1] = bf2f((unsigned short)(v.x >> 16));
    f[2] = bf2f((unsigned short)(v.y & 0xffff)); f[3] = bf2f((unsigned short)(v.y >> 16));
    f[4] = bf2f((unsigned short)(v.z & 0xffff)); f[5] = bf2f((unsigned short)(v.z >> 16));
    f[6] = bf2f((unsigned short)(v.w & 0xffff)); f[7] = bf2f((unsigned short)(v.w >> 16));
}

// ---------------------------------------------------------------------------
// Index dtype detection + canonicalization
// ---------------------------------------------------------------------------
__global__ void detect_kernel(const int* __restrict__ ei, int* __restrict__ flag)
{
    int lane = threadIdx.x;
    int v = ei[2 * lane + 1];
    unsigned long long b = __ballot(v != 0);
    if (lane == 0) *flag = (b != 0ULL) ? 1 : 0;
}

__global__ void normidx_kernel(const int* __restrict__ ei, const int* __restrict__ flag,
                               int* __restrict__ s32, int* __restrict__ d32)
{
    int e = blockIdx.x * blockDim.x + threadIdx.x;
    if (e >= NEDGES) return;
    int s, d;
    if (*flag) { s = ei[e]; d = ei[NEDGES + e]; }
    else       { s = ei[2 * e]; d = ei[2 * (NEDGES + e)]; }
    s32[e] = min(max(s, 0), NNODES - 1);
    d32[e] = min(max(d, 0), NNODES - 1);
}

__global__ void degree_kernel(const int* __restrict__ dst, int* __restrict__ deg)
{
    int e = blockIdx.x * blockDim.x + threadIdx.x;
    if (e < NEDGES) atomicAdd(&deg[dst[e]], 1);
}

// ---------------------------------------------------------------------------
// Exclusive scan over deg[0..NNODES) -> off, cursor. One 1024-thread block.
// ---------------------------------------------------------------------------
#define SCAN_T 1024
__global__ void scan_kernel(const int* __restrict__ deg, int* __restrict__ off,
                            int* __restrict__ cursor)
{
    __shared__ int part[SCAN_T];
    const int t = threadIdx.x;
    const int CH = (NNODES + SCAN_T - 1) / SCAN_T;
    const int base = t * CH;
    int s = 0;
    for (int i = 0; i < CH; ++i) {
        int idx = base + i;
        if (idx < NNODES) s += deg[idx];
    }
    part[t] = s;
    __syncthreads();
    for (int d = 1; d < SCAN_T; d <<= 1) {
        int v = (t >= d) ? part[t - d] : 0;
        __syncthreads();
        part[t] += v;
        __syncthreads();
    }
    int run = (t == 0) ? 0 : part[t - 1];
    for (int i = 0; i < CH; ++i) {
        int idx = base + i;
        if (idx < NNODES) {
            off[idx] = run;
            cursor[idx] = run;
            run += deg[idx];
        }
    }
    if (t == SCAN_T - 1) off[NNODES] = run;
}

__global__ void scatter_kernel(const int* __restrict__ s32, const int* __restrict__ d32,
                               int* __restrict__ cursor,
                               int* __restrict__ sp, int* __restrict__ dp, int* __restrict__ ep)
{
    int e = blockIdx.x * blockDim.x + threadIdx.x;
    if (e >= NEDGES) return;
    int d = d32[e];
    int p = atomicAdd(&cursor[d], 1);
    sp[p] = s32[e];
    dp[p] = d;
    ep[p] = e;
}

// ---------------------------------------------------------------------------
// Weight transpose+convert: W [L][K][N] fp32 -> WT [L][N][K] bf16
// ---------------------------------------------------------------------------
__global__ void transpose_kernel(const float* __restrict__ W, unsigned short* __restrict__ WT,
                                 int K, int N, int L)
{
    long idx = (long)blockIdx.x * 256 + threadIdx.x;
    long tot = (long)L * K * N;
    if (idx >= tot) return;
    int kn = (int)(idx % ((long)K * N));
    int l  = (int)(idx / ((long)K * N));
    int k = kn / N;
    int n = kn % N;
    WT[(long)l * K * N + (long)n * K + k] = f2bf(W[idx]);
}

// ---------------------------------------------------------------------------
// Encoder into permuted layout: ef[p] = enc(ea[ep[p]])
// ---------------------------------------------------------------------------
__global__ void encode_kernel(const float* __restrict__ ea,
                              const float* __restrict__ w,
                              const float* __restrict__ b,
                              const int* __restrict__ ep,
                              unsigned short* __restrict__ ef)
{
    int idx = blockIdx.x * blockDim.x + threadIdx.x;
    int p = idx >> 5;
    if (p >= NEDGES) return;
    int e = ep[p];
    int j = (idx & 31) << 2;
    float a0 = ea[e * 3 + 0], a1 = ea[e * 3 + 1], a2 = ea[e * 3 + 2];
    float4 w0 = *(const float4*)(w + 0 * HIDDEN + j);
    float4 w1 = *(const float4*)(w + 1 * HIDDEN + j);
    float4 w2 = *(const float4*)(w + 2 * HIDDEN + j);
    float4 bb = *(const float4*)(b + j);
    ushort4 o;
    o.x = f2bf(fmaf(a0, w0.x, fmaf(a1, w1.x, fmaf(a2, w2.x, bb.x))));
    o.y = f2bf(fmaf(a0, w0.y, fmaf(a1, w1.y, fmaf(a2, w2.y, bb.y))));
    o.z = f2bf(fmaf(a0, w0.z, fmaf(a1, w1.z, fmaf(a2, w2.z, bb.z))));
    o.w = f2bf(fmaf(a0, w0.w, fmaf(a1, w1.w, fmaf(a2, w2.w, bb.w))));
    *(ushort4*)(ef + (long)p * HIDDEN + j) = o;
}

// ---------------------------------------------------------------------------
// MFMA edge layer — EXACT round-10 best variant (4 waves, 128-edge tile).
// ---------------------------------------------------------------------------
__global__ __launch_bounds__(256, 3)
void edge_layer_mfma(const unsigned short* __restrict__ Xa,   // [N][128] bf16
                     const unsigned short* __restrict__ Xb,   // [N][128] bf16
                     unsigned short* __restrict__ ef,
                     float* __restrict__ sums,
                     const int* __restrict__ sp,
                     const int* __restrict__ dp,
                     const unsigned short* __restrict__ W1T,  // [128][384] bf16; W1c at k+256
                     const float* __restrict__ b1,
                     const unsigned short* __restrict__ W2T,  // [128][128] bf16
                     const float* __restrict__ b2)
{
    __shared__ __align__(16) unsigned char buf[45056];
    unsigned short* As = (unsigned short*)buf;
    unsigned short* Hs = (unsigned short*)buf;
    unsigned short* Bs = (unsigned short*)(buf + 34816);
    __shared__ int dv[128];
    __shared__ int sv[128];

    const int tid = threadIdx.x;
    const long eb = (long)blockIdx.x * 128;
    if (tid < 128) dv[tid]       = dp[eb + tid];
    else           sv[tid - 128] = sp[eb + tid - 128];

    const int lane = tid & 63;
    const int wv   = tid >> 6;
    const int mn   = lane & 15;
    const int q    = lane >> 4;
    const int rr   = tid >> 1;
    const int o    = (tid & 1) << 4;
    const int bn   = tid >> 1;
    const int bk   = (tid & 1) << 4;

    f32x4 acc[2][8];
#pragma unroll
    for (int h = 0; h < 2; ++h)
#pragma unroll
        for (int t = 0; t < 8; ++t) acc[h][t] = (f32x4)0.0f;

    short8 efold0[4], efold1[4];

    uint4 pa0, pa1, pw0, pw1;
    {
        const unsigned short* epp = ef + (eb + rr) * HIDDEN + o;
        pa0 = *(const uint4*)epp;
        pa1 = *(const uint4*)(epp + 8);
        const unsigned short* wp = W1T + (long)bn * 384 + 256 + bk;
        pw0 = *(const uint4*)wp;
        pw1 = *(const uint4*)(wp + 8);
    }

    for (int c = 0; c < 4; ++c) {
        *(uint4*)&As[rr * 40 + o]      = pa0;
        *(uint4*)&As[rr * 40 + o + 8]  = pa1;
        *(uint4*)&Bs[bn * 40 + bk]     = pw0;
        *(uint4*)&Bs[bn * 40 + bk + 8] = pw1;
        __syncthreads();

        if (c + 1 < 4) {
            const int cn = c + 1;
            const unsigned short* epp = ef + (eb + rr) * HIDDEN + (cn << 5) + o;
            pa0 = *(const uint4*)epp;
            pa1 = *(const uint4*)(epp + 8);
            const unsigned short* wp = W1T + (long)bn * 384 + 256 + (cn << 5) + bk;
            pw0 = *(const uint4*)wp;
            pw1 = *(const uint4*)(wp + 8);
        }

        short8 af0 = *(short8*)&As[(wv * 32 + mn) * 40 + (q << 3)];
        short8 af1 = *(short8*)&As[(wv * 32 + 16 + mn) * 40 + (q << 3)];
        efold0[c] = af0;
        efold1[c] = af1;
#pragma unroll
        for (int nt = 0; nt < 8; ++nt) {
            short8 bf = *(short8*)&Bs[(nt * 16 + mn) * 40 + (q << 3)];
            acc[0][nt] = __builtin_amdgcn_mfma_f32_16x16x32_bf16(af0, bf, acc[0][nt], 0, 0, 0);
            acc[1][nt] = __builtin_amdgcn_mfma_f32_16x16x32_bf16(af1, bf, acc[1][nt], 0, 0, 0);
        }
        __syncthreads();
    }

    // ---- pre -> Hs (C-layout, own wave band) ----
#pragma unroll
    for (int h = 0; h < 2; ++h)
#pragma unroll
        for (int nt = 0; nt < 8; ++nt)
#pragma unroll
            for (int r = 0; r < 4; ++r)
                Hs[(wv * 32 + h * 16 + q * 4 + r) * 136 + nt * 16 + mn] = f2bf(acc[h][nt][r]);

    // ---- H = relu(pre + Xa[dst] + Xb[src] + b1), row-major, vector gather ----
    {
        const int row  = wv * 32 + (lane >> 1);
        const int ch   = (lane & 1) << 6;
        const unsigned short* xap = Xa + (long)dv[row] * HIDDEN + ch;
        const unsigned short* xbp = Xb + (long)sv[row] * HIDDEN + ch;
        unsigned short* hp = &Hs[row * 136 + ch];
#pragma unroll
        for (int i = 0; i < 8; ++i) {
            uint4 va = *(const uint4*)(xap + (i << 3));
            uint4 vb = *(const uint4*)(xbp + (i << 3));
            uint4 vp = *(uint4*)(hp + (i << 3));
            float fa[8], fb[8], fp[8];
            unpack8(va, fa); unpack8(vb, fb); unpack8(vp, fp);
            const float* bp = b1 + ch + (i << 3);
            uint4 nw;
            float h0 = fmaxf(fp[0] + fa[0] + fb[0] + bp[0], 0.0f);
            float h1 = fmaxf(fp[1] + fa[1] + fb[1] + bp[1], 0.0f);
            float h2 = fmaxf(fp[2] + fa[2] + fb[2] + bp[2], 0.0f);
            float h3 = fmaxf(fp[3] + fa[3] + fb[3] + bp[3], 0.0f);
            float h4 = fmaxf(fp[4] + fa[4] + fb[4] + bp[4], 0.0f);
            float h5 = fmaxf(fp[5] + fa[5] + fb[5] + bp[5], 0.0f);
            float h6 = fmaxf(fp[6] + fa[6] + fb[6] + bp[6], 0.0f);
            float h7 = fmaxf(fp[7] + fa[7] + fb[7] + bp[7], 0.0f);
            nw.x = pack2(h0, h1); nw.y = pack2(h2, h3);
            nw.z = pack2(h4, h5); nw.w = pack2(h6, h7);
            *(uint4*)(hp + (i << 3)) = nw;
        }
    }
    // No barrier: GEMM2 A-frags read only this wave's band (DS wave-ordered).

    f32x4 acc2[2][8];
#pragma unroll
    for (int h = 0; h < 2; ++h)
#pragma unroll
        for (int t = 0; t < 8; ++t) acc2[h][t] = (f32x4)0.0f;
    {
        const unsigned short* wp = W2T + (long)bn * 128 + bk;
        pw0 = *(const uint4*)wp;
        pw1 = *(const uint4*)(wp + 8);
    }
    for (int c = 0; c < 4; ++c) {
        *(uint4*)&Bs[bn * 40 + bk]     = pw0;
        *(uint4*)&Bs[bn * 40 + bk + 8] = pw1;
        __syncthreads();
        if (c + 1 < 4) {
            const unsigned short* wp = W2T + (long)bn * 128 + ((c + 1) << 5) + bk;
            pw0 = *(const uint4*)wp;
            pw1 = *(const uint4*)(wp + 8);
        }
        short8 af0 = *(short8*)&Hs[(wv * 32 + mn) * 136 + (c << 5) + (q << 3)];
        short8 af1 = *(short8*)&Hs[(wv * 32 + 16 + mn) * 136 + (c << 5) + (q << 3)];
#pragma unroll
        for (int nt = 0; nt < 8; ++nt) {
            short8 bf = *(short8*)&Bs[(nt * 16 + mn) * 40 + (q << 3)];
            acc2[0][nt] = __builtin_amdgcn_mfma_f32_16x16x32_bf16(af0, bf, acc2[0][nt], 0, 0, 0);
            acc2[1][nt] = __builtin_amdgcn_mfma_f32_16x16x32_bf16(af1, bf, acc2[1][nt], 0, 0, 0);
        }
        __syncthreads();
    }

    // ---- m = acc2 + b2 -> Hs (C-layout, own band) ----
#pragma unroll
    for (int h = 0; h < 2; ++h)
#pragma unroll
        for (int nt = 0; nt < 8; ++nt) {
            float b2v = b2[nt * 16 + mn];
#pragma unroll
            for (int r = 0; r < 4; ++r)
                Hs[(wv * 32 + h * 16 + q * 4 + r) * 136 + nt * 16 + mn] = f2bf(acc2[h][nt][r] + b2v);
        }

    // ---- ef_new = ef_old(regs) + m : A-frag order, no re-read ----
#pragma unroll
    for (int h = 0; h < 2; ++h) {
        const int row = wv * 32 + h * 16 + mn;
        unsigned short* ep_ = ef + (eb + row) * HIDDEN + (q << 3);
#pragma unroll
        for (int c = 0; c < 4; ++c) {
            uint4 mh = *(uint4*)&Hs[row * 136 + (c << 5) + (q << 3)];
            float m[8], e[8];
            unpack8(mh, m);
            short8 eo = h ? efold1[c] : efold0[c];
            uint4 eu = *(uint4*)&eo;
            unpack8(eu, e);
            uint4 nw;
            nw.x = pack2(e[0] + m[0], e[1] + m[1]);
            nw.y = pack2(e[2] + m[2], e[3] + m[3]);
            nw.z = pack2(e[4] + m[4], e[5] + m[5]);
            nw.w = pack2(e[6] + m[6], e[7] + m[7]);
            *(uint4*)(ep_ + (c << 5)) = nw;
        }
    }

    // ---- segmented reduction by dst-run (own band rows, barrier-free) ----
    {
        const int cp = (tid & 63) << 1;
        const int qr = tid >> 6;
        float s0 = 0.0f, s1 = 0.0f;
        int cur = dv[qr * 32];
        for (int r = 0; r < 32; ++r) {
            const int row = qr * 32 + r;
            const int d = dv[row];
            if (d != cur) {
                atomicAdd(&sums[(long)cur * HIDDEN + cp], s0);
                atomicAdd(&sums[(long)cur * HIDDEN + cp + 1], s1);
                s0 = 0.0f; s1 = 0.0f;
                cur = d;
            }
            unsigned int u = *(unsigned int*)&Hs[row * 136 + cp];
            s0 += bf2f((unsigned short)(u & 0xffff));
            s1 += bf2f((unsigned short)(u >> 16));
        }
        atomicAdd(&sums[(long)cur * HIDDEN + cp], s0);
        atomicAdd(&sums[(long)cur * HIDDEN + cp + 1], s1);
    }
}

// ---------------------------------------------------------------------------
// MFMA node layer — EXACT round-14 variant (As-under-Hs aliasing, 27.9 KB LDS,
// 5 blocks/CU).
// ---------------------------------------------------------------------------
__global__ __launch_bounds__(256, 5)
void node_layer_mfma(float* __restrict__ x,
                     float* __restrict__ sums,
                     const int* __restrict__ deg,
                     const unsigned short* __restrict__ N1T,  // [128][256] bf16
                     const float* __restrict__ b1,
                     const unsigned short* __restrict__ N2T,  // [128][128] bf16
                     const float* __restrict__ b2,
                     const unsigned short* __restrict__ W1Tn, // [128][384] next layer (or null)
                     unsigned short* __restrict__ Xa,
                     unsigned short* __restrict__ Xb)
{
    // 0     .. 17408 : Hs (64 x 136) / As (64 x 40) aliased
    // 17408 .. 27648 : Bs (128 x 40)
    __shared__ __align__(16) unsigned char nbuf[27648];
    unsigned short* As = (unsigned short*)nbuf;
    unsigned short* Hs = (unsigned short*)nbuf;
    unsigned short* Bs = (unsigned short*)(nbuf + 17408);
    __shared__ float cInv[64];

    const int tid = threadIdx.x;
    const long n0 = (long)blockIdx.x * 64;
    if (tid < 64) {
        long n = n0 + tid;
        cInv[tid] = (n < NNODES) ? 1.0f / fmaxf((float)deg[n], 1.0f) : 0.0f;
    }

    const int lane = tid & 63;
    const int wv   = tid >> 6;
    const int mn   = lane & 15;
    const int q    = lane >> 4;
    const int srow = tid >> 2;
    const int sseg = tid & 3;
    const int bn   = tid >> 1;
    const int bk   = (tid & 1) << 4;

    long nr = n0 + srow;
    if (nr >= NNODES) nr = NNODES - 1;

    __syncthreads();

    f32x4 acc[8];
#pragma unroll
    for (int t = 0; t < 8; ++t) acc[t] = (f32x4)0.0f;

    float4 pa0, pa1;
    uint4 pb0, pb1;
    {
        const float* spx = x + nr * HIDDEN + (sseg << 3);
        pa0 = *(const float4*)spx;
        pa1 = *(const float4*)(spx + 4);
        const unsigned short* wp = N1T + (long)bn * 256 + bk;
        pb0 = *(const uint4*)wp;
        pb1 = *(const uint4*)(wp + 8);
    }
    float scCur = 1.0f;
    for (int c = 0; c < 8; ++c) {
        {
            uint4 w;
            w.x = pack2(pa0.x * scCur, pa0.y * scCur); w.y = pack2(pa0.z * scCur, pa0.w * scCur);
            w.z = pack2(pa1.x * scCur, pa1.y * scCur); w.w = pack2(pa1.z * scCur, pa1.w * scCur);
            *(uint4*)&As[srow * 40 + (sseg << 3)] = w;
        }
        *(uint4*)&Bs[bn * 40 + bk]     = pb0;
        *(uint4*)&Bs[bn * 40 + bk + 8] = pb1;
        __syncthreads();
        if (c + 1 < 8) {
            const int cn = c + 1;
            const float* base = (cn < 4) ? x : sums;
            scCur = (cn < 4) ? 1.0f : cInv[srow];
            const float* spx = base + nr * HIDDEN + ((cn & 3) << 5) + (sseg << 3);
            pa0 = *(const float4*)spx;
            pa1 = *(const float4*)(spx + 4);
            const unsigned short* wp = N1T + (long)bn * 256 + (cn << 5) + bk;
            pb0 = *(const uint4*)wp;
            pb1 = *(const uint4*)(wp + 8);
        }
        short8 af = *(short8*)&As[(wv * 16 + mn) * 40 + (q << 3)];
#pragma unroll
        for (int nt = 0; nt < 8; ++nt) {
            short8 bf = *(short8*)&Bs[(nt * 16 + mn) * 40 + (q << 3)];
            acc[nt] = __builtin_amdgcn_mfma_f32_16x16x32_bf16(af, bf, acc[nt], 0, 0, 0);
        }
        __syncthreads();
    }
    // As reads done (final barrier above) -> Hs alias safe.

    // zero own sums rows for the next layer
    {
        long row = n0 + srow;
        if (row < NNODES) {
            float4 z = make_float4(0.f, 0.f, 0.f, 0.f);
            float* p = sums + row * HIDDEN + (sseg << 5);
#pragma unroll
            for (int i = 0; i < 8; ++i) ((float4*)p)[i] = z;
        }
    }

#pragma unroll
    for (int nt = 0; nt < 8; ++nt) {
        float b1v = b1[nt * 16 + mn];
#pragma unroll
        for (int r = 0; r < 4; ++r) {
            float hv = fmaxf(acc[nt][r] + b1v, 0.0f);
            Hs[(wv * 16 + q * 4 + r) * 136 + nt * 16 + mn] = f2bf(hv);
        }
    }

    f32x4 acc2[8];
#pragma unroll
    for (int t = 0; t < 8; ++t) acc2[t] = (f32x4)0.0f;
    {
        const unsigned short* wp = N2T + (long)bn * 128 + bk;
        pb0 = *(const uint4*)wp;
        pb1 = *(const uint4*)(wp + 8);
    }
    for (int c = 0; c < 4; ++c) {
        *(uint4*)&Bs[bn * 40 + bk]     = pb0;
        *(uint4*)&Bs[bn * 40 + bk + 8] = pb1;
        __syncthreads();
        if (c + 1 < 4) {
            const unsigned short* wp = N2T + (long)bn * 128 + ((c + 1) << 5) + bk;
            pb0 = *(const uint4*)wp;
            pb1 = *(const uint4*)(wp + 8);
        }
        short8 af = *(short8*)&Hs[(wv * 16 + mn) * 136 + (c << 5) + (q << 3)];
#pragma unroll
        for (int nt = 0; nt < 8; ++nt) {
            short8 bf = *(short8*)&Bs[(nt * 16 + mn) * 40 + (q << 3)];
            acc2[nt] = __builtin_amdgcn_mfma_f32_16x16x32_bf16(af, bf, acc2[nt], 0, 0, 0);
        }
        __syncthreads();
    }

    // ---- xnew = x + acc2 + b2 (exact fp32); stage xnew bf16 into Hs ----
#pragma unroll
    for (int nt = 0; nt < 8; ++nt) {
        float b2v = b2[nt * 16 + mn];
#pragma unroll
        for (int r = 0; r < 4; ++r) {
            long row = n0 + wv * 16 + q * 4 + r;
            float xn = 0.0f;
            if (row < NNODES) {
                float* p = x + row * HIDDEN + nt * 16 + mn;
                xn = *p + acc2[nt][r] + b2v;
                *p = xn;
            }
            Hs[(wv * 16 + q * 4 + r) * 136 + nt * 16 + mn] = f2bf(xn);
        }
    }

    // ---- Xa/Xb for next layer: xnew @ W1a / W1b ----
    if (W1Tn) {
#pragma unroll
        for (int half = 0; half < 2; ++half) {
            f32x4 accN[8];
#pragma unroll
            for (int t = 0; t < 8; ++t) accN[t] = (f32x4)0.0f;
            const int kbase = half << 7;
            {
                const unsigned short* wp = W1Tn + (long)bn * 384 + kbase + bk;
                pb0 = *(const uint4*)wp;
                pb1 = *(const uint4*)(wp + 8);
            }
            for (int c = 0; c < 4; ++c) {
                *(uint4*)&Bs[bn * 40 + bk]     = pb0;
                *(uint4*)&Bs[bn * 40 + bk + 8] = pb1;
                __syncthreads();
                if (c + 1 < 4) {
                    const unsigned short* wp = W1Tn + (long)bn * 384 + kbase + ((c + 1) << 5) + bk;
                    pb0 = *(const uint4*)wp;
                    pb1 = *(const uint4*)(wp + 8);
                }
                short8 af = *(short8*)&Hs[(wv * 16 + mn) * 136 + (c << 5) + (q << 3)];
#pragma unroll
                for (int nt = 0; nt < 8; ++nt) {
                    short8 bf = *(short8*)&Bs[(nt * 16 + mn) * 40 + (q << 3)];
                    accN[nt] = __builtin_amdgcn_mfma_f32_16x16x32_bf16(af, bf, accN[nt], 0, 0, 0);
                }
                __syncthreads();
            }
            unsigned short* Xout = half ? Xb : Xa;
#pragma unroll
            for (int nt = 0; nt < 8; ++nt) {
#pragma unroll
                for (int r = 0; r < 4; ++r) {
                    long row = n0 + wv * 16 + q * 4 + r;
                    if (row < NNODES) {
                        Xout[row * HIDDEN + nt * 16 + mn] = f2bf(accN[nt][r]);
                    }
                }
            }
        }
    }
}

// ---------------------------------------------------------------------------
// Decoder + row L2-normalize (one wave per node)
// ---------------------------------------------------------------------------
__global__ void decode_kernel(const float* __restrict__ x,
                              const float* __restrict__ w,
                              const float* __restrict__ b,
                              float* __restrict__ out)
{
    int gid = blockIdx.x * blockDim.x + threadIdx.x;
    int node = gid >> 6;
    int lane = threadIdx.x & 63;
    if (node >= NNODES) return;
    float a0 = 0.f, a1 = 0.f, a2 = 0.f;
#pragma unroll
    for (int k = lane; k < HIDDEN; k += 64) {
        float xv = x[(long)node * HIDDEN + k];
        a0 = fmaf(xv, w[k * 3 + 0], a0);
        a1 = fmaf(xv, w[k * 3 + 1], a1);
        a2 = fmaf(xv, w[k * 3 + 2], a2);
    }
#pragma unroll
    for (int off = 32; off > 0; off >>= 1) {
        a0 += __shfl_down(a0, off);
        a1 += __shfl_down(a1, off);
        a2 += __shfl_down(a2, off);
    }
    if (lane == 0) {
        a0 += b[0]; a1 += b[1]; a2 += b[2];
        float nrm = sqrtf(a0 * a0 + a1 * a1 + a2 * a2);
        float inv = 1.0f / fmaxf(nrm, 1e-12f);
        out[(long)node * 3 + 0] = a0 * inv;
        out[(long)node * 3 + 1] = a1 * inv;
        out[(long)node * 3 + 2] = a2 * inv;
    }
}

// ---------------------------------------------------------------------------
extern "C" void kernel_launch(void* const* d_in, const int* in_sizes, int n_in,
                              void* d_out, int out_size, void* d_ws, size_t ws_size,
                              hipStream_t stream)
{
    const float* edge_attr = (const float*)d_in[1];
    const int*   ei        = (const int*)d_in[2];
    const float* enc_w     = (const float*)d_in[3];
    const float* enc_b     = (const float*)d_in[4];
    const float* dec_w     = (const float*)d_in[5];
    const float* dec_b     = (const float*)d_in[6];
    const float* edge_w1   = (const float*)d_in[7];
    const float* edge_b1   = (const float*)d_in[8];
    const float* edge_w2   = (const float*)d_in[9];
    const float* edge_b2   = (const float*)d_in[10];
    const float* node_w1   = (const float*)d_in[11];
    const float* node_b1   = (const float*)d_in[12];
    const float* node_w2   = (const float*)d_in[13];
    const float* node_b2   = (const float*)d_in[14];

    // workspace layout (bytes), 16B-aligned, total ~255.4 MB
    char* ws = (char*)d_ws;
    unsigned short* ef  = (unsigned short*)(ws);                  // 163,840,000
    float* x      = (float*)(ws + 163840000L);                    //  25,600,000
    float* sums   = (float*)(ws + 189440000L);                    //  25,600,000
    int*   src32  = (int*)  (ws + 215040000L);                    //   2,560,000
    int*   dst32  = (int*)  (ws + 217600000L);                    //   2,560,000
    int*   sp     = (int*)  (ws + 220160000L);                    //   2,560,000
    int*   dp     = (int*)  (ws + 222720000L);                    //   2,560,000
    int*   eperm  = (int*)  (ws + 225280000L);                    //   2,560,000
    int*   deg    = (int*)  (ws + 227840000L);                    //     200,704
    int*   off    = (int*)  (ws + 228040704L);                    //     200,704
    int*   cursor = (int*)  (ws + 228241408L);                    //     200,704
    int*   flag   = (int*)  (ws + 228442112L);                    //          64
    unsigned short* W1T = (unsigned short*)(ws + 228442176L);     //     589,824
    unsigned short* W2T = (unsigned short*)(ws + 229032000L);     //     196,608
    unsigned short* N1T = (unsigned short*)(ws + 229228608L);     //     393,216
    unsigned short* N2T = (unsigned short*)(ws + 229621824L);     //     196,608
    unsigned short* Xa  = (unsigned short*)(ws + 229818432L);     //  12,800,000
    unsigned short* Xb  = (unsigned short*)(ws + 242618432L);     //  12,800,000
    // end: 255,418,432

    float* out = (float*)d_out;

    hipMemsetAsync(x, 0, (size_t)NNODES * HIDDEN * sizeof(float), stream);
    hipMemsetAsync(sums, 0, (size_t)NNODES * HIDDEN * sizeof(float), stream);
    hipMemsetAsync(deg, 0, 200704, stream);
    hipMemsetAsync(Xa, 0, 25600000, stream);   // Xa + Xb (contiguous)

    detect_kernel<<<1, 64, 0, stream>>>(ei, flag);
    normidx_kernel<<<(NEDGES + 255) / 256, 256, 0, stream>>>(ei, flag, src32, dst32);
    degree_kernel<<<(NEDGES + 255) / 256, 256, 0, stream>>>(dst32, deg);
    scan_kernel<<<1, SCAN_T, 0, stream>>>(deg, off, cursor);
    scatter_kernel<<<(NEDGES + 255) / 256, 256, 0, stream>>>(src32, dst32, cursor, sp, dp, eperm);
    encode_kernel<<<(NEDGES * 32 + 255) / 256, 256, 0, stream>>>(edge_attr, enc_w, enc_b, eperm, ef);

    transpose_kernel<<<(6 * 384 * 128 + 255) / 256, 256, 0, stream>>>(edge_w1, W1T, 384, 128, 6);
    transpose_kernel<<<(6 * 128 * 128 + 255) / 256, 256, 0, stream>>>(edge_w2, W2T, 128, 128, 6);
    transpose_kernel<<<(6 * 256 * 128 + 255) / 256, 256, 0, stream>>>(node_w1, N1T, 256, 128, 6);
    transpose_kernel<<<(6 * 128 * 128 + 255) / 256, 256, 0, stream>>>(node_w2, N2T, 128, 128, 6);

    for (int l = 0; l < NLAYERS; ++l) {
        edge_layer_mfma<<<NEDGES / 128, 256, 0, stream>>>(
            Xa, Xb, ef, sums, sp, dp,
            W1T + (long)l * 384 * 128, edge_b1 + (long)l * HIDDEN,
            W2T + (long)l * 128 * 128, edge_b2 + (long)l * HIDDEN);
        const unsigned short* w1next = (l + 1 < NLAYERS) ? (W1T + (long)(l + 1) * 384 * 128) : nullptr;
        node_layer_mfma<<<(NNODES + 63) / 64, 256, 0, stream>>>(
            x, sums, deg,
            N1T + (long)l * 256 * 128, node_b1 + (long)l * HIDDEN,
            N2T + (long)l * 128 * 128, node_b2 + (long)l * HIDDEN,
            w1next, Xa, Xb);
    }

    decode_kernel<<<(NNODES * 64 + 255) / 256, 256, 0, stream>>>(x, dec_w, dec_b, out);
}